// Round 3
// baseline (2607.096 us; speedup 1.0000x reference)
//
#include <hip/hip_runtime.h>
#include <math.h>

// Problem constants: B=2, T=2048, E=1024, H=16, D=64
#define TT 2048
#define EE 1024
#define HH 16
#define DD 64
#define BB 2

#define NEGV (-1000000000.0f)

// ---------------------------------------------------------------------------
// Threefry-2x32, JAX *partitionable* stream (default since jax 0.4.3x).
// For flat element index f (row-major over (B,T,T)): 64-bit counter = f,
// split as (x0=hi32=0, x1=lo32=f); key=(0,42); 20 rounds; 32-bit draw is
// the XOR-fold of the two output words: bits = v0_final ^ v1_final.
// ---------------------------------------------------------------------------
__device__ __forceinline__ unsigned int rotl32(unsigned int x, int r) {
    return (x << r) | (x >> (32 - r));
}

__device__ __forceinline__ float gumbel_for(unsigned int f) {
    const unsigned int ks0 = 0u;
    const unsigned int ks1 = 42u;
    const unsigned int ks2 = 0x1BD11BDAu ^ ks0 ^ ks1;

    unsigned int v0 = 0u + ks0;   // x0 = hi32(flat) = 0
    unsigned int v1 = f  + ks1;   // x1 = lo32(flat) = f

    // round group 1 (rot set A), then key add
    v0 += v1; v1 = rotl32(v1, 13); v1 ^= v0;
    v0 += v1; v1 = rotl32(v1, 15); v1 ^= v0;
    v0 += v1; v1 = rotl32(v1, 26); v1 ^= v0;
    v0 += v1; v1 = rotl32(v1,  6); v1 ^= v0;
    v0 += ks1; v1 += ks2 + 1u;
    // group 2 (rot set B)
    v0 += v1; v1 = rotl32(v1, 17); v1 ^= v0;
    v0 += v1; v1 = rotl32(v1, 29); v1 ^= v0;
    v0 += v1; v1 = rotl32(v1, 16); v1 ^= v0;
    v0 += v1; v1 = rotl32(v1, 24); v1 ^= v0;
    v0 += ks2; v1 += ks0 + 2u;
    // group 3 (A)
    v0 += v1; v1 = rotl32(v1, 13); v1 ^= v0;
    v0 += v1; v1 = rotl32(v1, 15); v1 ^= v0;
    v0 += v1; v1 = rotl32(v1, 26); v1 ^= v0;
    v0 += v1; v1 = rotl32(v1,  6); v1 ^= v0;
    v0 += ks0; v1 += ks1 + 3u;
    // group 4 (B)
    v0 += v1; v1 = rotl32(v1, 17); v1 ^= v0;
    v0 += v1; v1 = rotl32(v1, 29); v1 ^= v0;
    v0 += v1; v1 = rotl32(v1, 16); v1 ^= v0;
    v0 += v1; v1 = rotl32(v1, 24); v1 ^= v0;
    v0 += ks1; v1 += ks2 + 4u;
    // group 5 (A)
    v0 += v1; v1 = rotl32(v1, 13); v1 ^= v0;
    v0 += v1; v1 = rotl32(v1, 15); v1 ^= v0;
    v0 += v1; v1 = rotl32(v1, 26); v1 ^= v0;
    v0 += v1; v1 = rotl32(v1,  6); v1 ^= v0;
    v0 += ks2; v1 += ks0 + 5u;

    unsigned int bits = v0 ^ v1;  // partitionable 32-bit draw: XOR-fold
    unsigned int fb = (bits >> 9) | 0x3F800000u;
    float u01 = __uint_as_float(fb) - 1.0f;
    const float mn = 1e-6f;
    const float mx = 1.0f - 1e-6f;
    float u = fmaxf(mn, u01 * (mx - mn) + mn);
    return -logf(-logf(u));
}

// ---------------------------------------------------------------------------
// Kernel A: C[r,c] = hs[r,:] . W[c,:] + bias[c], r in [0,4096), c in [0,2048)
// c < 1024 -> Qbuf[r*1024+c];  c >= 1024 -> Kt[(b*16+h)*T*64 + t*64 + d]
// ---------------------------------------------------------------------------
__global__ __launch_bounds__(256) void qk_proj_kernel(
    const float* __restrict__ hs, const float* __restrict__ W,
    const float* __restrict__ bias,
    float* __restrict__ Qbuf, float* __restrict__ Kt)
{
    __shared__ float As[64][17];
    __shared__ float Ws[64][17];
    const int tid  = threadIdx.x;
    const int row0 = blockIdx.y * 64;
    const int col0 = blockIdx.x * 64;
    const int ty = tid >> 4, tx = tid & 15;
    const int lr = tid >> 2;          // 0..63
    const int lc = (tid & 3) * 4;     // 0,4,8,12

    float acc[4][4] = {};

    for (int k0 = 0; k0 < EE; k0 += 16) {
        float4 av = *(const float4*)(hs + (size_t)(row0 + lr) * EE + k0 + lc);
        float4 wv = *(const float4*)(W  + (size_t)(col0 + lr) * EE + k0 + lc);
        As[lr][lc + 0] = av.x; As[lr][lc + 1] = av.y;
        As[lr][lc + 2] = av.z; As[lr][lc + 3] = av.w;
        Ws[lr][lc + 0] = wv.x; Ws[lr][lc + 1] = wv.y;
        Ws[lr][lc + 2] = wv.z; Ws[lr][lc + 3] = wv.w;
        __syncthreads();
#pragma unroll
        for (int kk = 0; kk < 16; ++kk) {
            float a[4], b[4];
#pragma unroll
            for (int m = 0; m < 4; ++m) a[m] = As[ty * 4 + m][kk];
#pragma unroll
            for (int n = 0; n < 4; ++n) b[n] = Ws[tx * 4 + n][kk];
#pragma unroll
            for (int m = 0; m < 4; ++m)
#pragma unroll
                for (int n = 0; n < 4; ++n) acc[m][n] += a[m] * b[n];
        }
        __syncthreads();
    }

#pragma unroll
    for (int m = 0; m < 4; ++m) {
        const int r = row0 + ty * 4 + m;
        const int b = r >> 11;          // r / T
        const int t = r & (TT - 1);     // r % T
#pragma unroll
        for (int n = 0; n < 4; ++n) {
            const int c = col0 + tx * 4 + n;
            const float v = acc[m][n] + bias[c];
            if (c < EE) {
                Qbuf[(size_t)r * EE + c] = v;
            } else {
                const int cc = c - EE;
                const int h = cc >> 6;
                const int d = cc & 63;
                Kt[(((size_t)(b * HH + h)) * TT + t) * DD + d] = v;
            }
        }
    }
}

// ---------------------------------------------------------------------------
// Kernel B: one block per (b, i) row. Computes head-mean of masked softmax,
// adds Gumbel noise (exact JAX threefry), softmax -> dw row.
// ---------------------------------------------------------------------------
__global__ __launch_bounds__(256) void rowsoftmax_kernel(
    const float* __restrict__ Qbuf, const float* __restrict__ Kt,
    float* __restrict__ dw)
{
    __shared__ float qrow[EE];     // 4 KB
    __shared__ float srow[TT];     // 8 KB
    __shared__ float avg[TT];      // 8 KB
    __shared__ float red[256];     // 1 KB

    const int tid = threadIdx.x;
    const int blk = blockIdx.x;          // 0..B*T-1
    const int b = blk >> 11;
    const int i = blk & (TT - 1);
    float* dwrow = dw + (size_t)blk * TT;

    if (i == 0) {
        for (int j = tid; j < TT; j += 256) dwrow[j] = 0.0f;
        return;
    }

    for (int c = tid; c < EE; c += 256) qrow[c] = Qbuf[(size_t)blk * EE + c];
    for (int j = tid; j < TT; j += 256) avg[j] = 0.0f;
    __syncthreads();

    for (int h = 0; h < HH; ++h) {
        const float* Kh = Kt + ((size_t)(b * HH + h)) * TT * DD;
        float lmax = -3.4e38f;
        for (int j = tid; j < TT; j += 256) {
            float s = NEGV;
            if (j < i) {
                const float4* kp = (const float4*)(Kh + (size_t)j * DD);
                float a = 0.f;
#pragma unroll
                for (int q = 0; q < 16; ++q) {
                    float4 kv = kp[q];
                    a += qrow[h * DD + q * 4 + 0] * kv.x
                       + qrow[h * DD + q * 4 + 1] * kv.y
                       + qrow[h * DD + q * 4 + 2] * kv.z
                       + qrow[h * DD + q * 4 + 3] * kv.w;
                }
                s = a * 0.125f;   // 1/sqrt(64)
            }
            srow[j] = s;
            lmax = fmaxf(lmax, s);
        }
        red[tid] = lmax; __syncthreads();
        for (int st = 128; st > 0; st >>= 1) {
            if (tid < st) red[tid] = fmaxf(red[tid], red[tid + st]);
            __syncthreads();
        }
        const float m = red[0]; __syncthreads();

        float lsum = 0.f;
        for (int j = tid; j < TT; j += 256) {
            float e = (j < i) ? expf(srow[j] - m) : 0.f;
            srow[j] = e;
            lsum += e;
        }
        red[tid] = lsum; __syncthreads();
        for (int st = 128; st > 0; st >>= 1) {
            if (tid < st) red[tid] += red[tid + st];
            __syncthreads();
        }
        const float inv = 1.0f / (red[0] * (float)HH);
        __syncthreads();
        for (int j = tid; j < TT; j += 256) avg[j] += srow[j] * inv;
        __syncthreads();
    }

    // dw row: logits + gumbel, softmax with TAU = 2
    const unsigned int flatbase = ((unsigned int)blk) * (unsigned int)TT;
    float lmax = -3.4e38f;
    for (int j = tid; j < TT; j += 256) {
        const float logit = (j < i) ? fminf(fmaxf(avg[j], -40.0f), 40.0f) : NEGV;
        const float g = gumbel_for(flatbase + (unsigned int)j);
        const float z = (logit + g) * 0.5f;
        srow[j] = z;
        lmax = fmaxf(lmax, z);
    }
    red[tid] = lmax; __syncthreads();
    for (int st = 128; st > 0; st >>= 1) {
        if (tid < st) red[tid] = fmaxf(red[tid], red[tid + st]);
        __syncthreads();
    }
    const float m = red[0]; __syncthreads();

    float lsum = 0.f;
    for (int j = tid; j < TT; j += 256) {
        float e = expf(srow[j] - m);
        srow[j] = e;
        lsum += e;
    }
    red[tid] = lsum; __syncthreads();
    for (int st = 128; st > 0; st >>= 1) {
        if (tid < st) red[tid] += red[tid + st];
        __syncthreads();
    }
    const float inv = 1.0f / red[0];
    for (int j = tid; j < TT; j += 256) dwrow[j] = srow[j] * inv;
}

// ---------------------------------------------------------------------------
// Kernel C: out[b] = dw[b] (TxT) @ hs[b] (TxE)
// ---------------------------------------------------------------------------
__global__ __launch_bounds__(256) void outgemm_kernel(
    const float* __restrict__ dw, const float* __restrict__ hs,
    float* __restrict__ out)
{
    __shared__ float As[64][17];
    __shared__ float Bs[16][68];

    const int b  = blockIdx.z;
    const int i0 = blockIdx.y * 64;
    const int e0 = blockIdx.x * 64;
    const float* A  = dw + (size_t)b * TT * TT;
    const float* Bm = hs + (size_t)b * TT * EE;
    float* C = out + (size_t)b * TT * EE;

    const int tid = threadIdx.x;
    const int ty = tid >> 4, tx = tid & 15;
    const int lrA = tid >> 2,  lcA = (tid & 3) * 4;
    const int lrB = tid >> 4,  lcB = (tid & 15) * 4;

    float acc[4][4] = {};

    for (int k0 = 0; k0 < TT; k0 += 16) {
        float4 av = *(const float4*)(A + (size_t)(i0 + lrA) * TT + k0 + lcA);
        As[lrA][lcA + 0] = av.x; As[lrA][lcA + 1] = av.y;
        As[lrA][lcA + 2] = av.z; As[lrA][lcA + 3] = av.w;
        float4 bv = *(const float4*)(Bm + (size_t)(k0 + lrB) * EE + e0 + lcB);
        Bs[lrB][lcB + 0] = bv.x; Bs[lrB][lcB + 1] = bv.y;
        Bs[lrB][lcB + 2] = bv.z; Bs[lrB][lcB + 3] = bv.w;
        __syncthreads();
#pragma unroll
        for (int kk = 0; kk < 16; ++kk) {
            float a[4], bb[4];
#pragma unroll
            for (int m = 0; m < 4; ++m) a[m] = As[ty * 4 + m][kk];
#pragma unroll
            for (int n = 0; n < 4; ++n) bb[n] = Bs[kk][tx * 4 + n];
#pragma unroll
            for (int m = 0; m < 4; ++m)
#pragma unroll
                for (int n = 0; n < 4; ++n) acc[m][n] += a[m] * bb[n];
        }
        __syncthreads();
    }

#pragma unroll
    for (int m = 0; m < 4; ++m)
#pragma unroll
        for (int n = 0; n < 4; ++n)
            C[(size_t)(i0 + ty * 4 + m) * EE + e0 + tx * 4 + n] = acc[m][n];
}

// ---------------------------------------------------------------------------
extern "C" void kernel_launch(void* const* d_in, const int* in_sizes, int n_in,
                              void* d_out, int out_size, void* d_ws, size_t ws_size,
                              hipStream_t stream) {
    const float* hs   = (const float*)d_in[0];   // (B,T,E)
    const float* W    = (const float*)d_in[1];   // (3E,E)
    const float* bias = (const float*)d_in[2];   // (3E,)
    float* out = (float*)d_out;                  // (B,T,E)

    char* ws = (char*)d_ws;
    float* Qbuf = (float*)ws;                                  // 4096*1024 f32 = 16 MB
    float* Kt   = (float*)(ws + (size_t)16 * 1024 * 1024);     // 2*16*2048*64 f32 = 16 MB
    float* dwb  = (float*)(ws + (size_t)32 * 1024 * 1024);     // 2*2048*2048 f32 = 32 MB

    // Kernel A: QK projection (M=4096, N=2048, K=1024)
    qk_proj_kernel<<<dim3(2048 / 64, 4096 / 64), 256, 0, stream>>>(hs, W, bias, Qbuf, Kt);

    // Kernel B: per-row fused softmax/mean/gumbel/softmax -> dw
    rowsoftmax_kernel<<<BB * TT, 256, 0, stream>>>(Qbuf, Kt, dwb);

    // Kernel C: out[b] = dw[b] @ hs[b]
    outgemm_kernel<<<dim3(EE / 64, TT / 64, BB), 256, 0, stream>>>(dwb, hs, out);
}

// Round 4
// 868.285 us; speedup vs baseline: 3.0026x; 3.0026x over previous
//
#include <hip/hip_runtime.h>
#include <math.h>

// Problem constants: B=2, T=2048, E=1024, H=16, D=64
#define TT 2048
#define EE 1024
#define HH 16
#define DD 64
#define BB 2

typedef __bf16 bf16_t;
typedef __attribute__((ext_vector_type(8))) __bf16 bf16x8;
typedef __attribute__((ext_vector_type(4))) float f32x4;

__device__ __forceinline__ unsigned short f2b(float v) {
    return __builtin_bit_cast(unsigned short, (__bf16)v);
}

// ---------------------------------------------------------------------------
// Threefry-2x32, JAX partitionable stream, key=(0,42). Verified round 3.
// ---------------------------------------------------------------------------
__device__ __forceinline__ unsigned int rotl32(unsigned int x, int r) {
    return (x << r) | (x >> (32 - r));
}

__device__ __forceinline__ float gumbel_for(unsigned int f) {
    const unsigned int ks0 = 0u;
    const unsigned int ks1 = 42u;
    const unsigned int ks2 = 0x1BD11BDAu ^ ks0 ^ ks1;

    unsigned int v0 = 0u + ks0;
    unsigned int v1 = f  + ks1;

    v0 += v1; v1 = rotl32(v1, 13); v1 ^= v0;
    v0 += v1; v1 = rotl32(v1, 15); v1 ^= v0;
    v0 += v1; v1 = rotl32(v1, 26); v1 ^= v0;
    v0 += v1; v1 = rotl32(v1,  6); v1 ^= v0;
    v0 += ks1; v1 += ks2 + 1u;
    v0 += v1; v1 = rotl32(v1, 17); v1 ^= v0;
    v0 += v1; v1 = rotl32(v1, 29); v1 ^= v0;
    v0 += v1; v1 = rotl32(v1, 16); v1 ^= v0;
    v0 += v1; v1 = rotl32(v1, 24); v1 ^= v0;
    v0 += ks2; v1 += ks0 + 2u;
    v0 += v1; v1 = rotl32(v1, 13); v1 ^= v0;
    v0 += v1; v1 = rotl32(v1, 15); v1 ^= v0;
    v0 += v1; v1 = rotl32(v1, 26); v1 ^= v0;
    v0 += v1; v1 = rotl32(v1,  6); v1 ^= v0;
    v0 += ks0; v1 += ks1 + 3u;
    v0 += v1; v1 = rotl32(v1, 17); v1 ^= v0;
    v0 += v1; v1 = rotl32(v1, 29); v1 ^= v0;
    v0 += v1; v1 = rotl32(v1, 16); v1 ^= v0;
    v0 += v1; v1 = rotl32(v1, 24); v1 ^= v0;
    v0 += ks1; v1 += ks2 + 4u;
    v0 += v1; v1 = rotl32(v1, 13); v1 ^= v0;
    v0 += v1; v1 = rotl32(v1, 15); v1 ^= v0;
    v0 += v1; v1 = rotl32(v1, 26); v1 ^= v0;
    v0 += v1; v1 = rotl32(v1,  6); v1 ^= v0;
    v0 += ks2; v1 += ks0 + 5u;

    unsigned int bits = v0 ^ v1;
    unsigned int fb = (bits >> 9) | 0x3F800000u;
    float u01 = __uint_as_float(fb) - 1.0f;
    const float mn = 1e-6f;
    const float mx = 1.0f - 1e-6f;
    float u = fmaxf(mn, u01 * (mx - mn) + mn);
    return -__logf(-__logf(u));
}

// ---------------------------------------------------------------------------
// Convert hs (4M f32) and W[0:2048] (2M f32) to bf16.
// ---------------------------------------------------------------------------
__global__ __launch_bounds__(256) void convert_kernel(
    const float* __restrict__ hs, const float* __restrict__ W,
    bf16_t* __restrict__ hsbf, bf16_t* __restrict__ Wbf)
{
    const int n1 = BB * TT * EE / 4;       // 1,048,576 float4 groups
    const int n2 = 2 * EE * EE / 4;        //   524,288
    const int total = n1 + n2;
    for (int idx = blockIdx.x * 256 + threadIdx.x; idx < total;
         idx += gridDim.x * 256) {
        float4 v = (idx < n1) ? ((const float4*)hs)[idx]
                              : ((const float4*)W)[idx - n1];
        ushort4 o;
        o.x = f2b(v.x); o.y = f2b(v.y); o.z = f2b(v.z); o.w = f2b(v.w);
        if (idx < n1) ((ushort4*)hsbf)[idx] = o;
        else          ((ushort4*)Wbf)[idx - n1] = o;
    }
}

// ---------------------------------------------------------------------------
// QK projection via MFMA: C[r,c] = hsbf[r,:].Wbf[c,:] + bias[c]
// r in [0,4096) (flat b*T+t), c in [0,2048). c<1024 -> Qbf (b,t,c) bf16;
// c>=1024 -> Kbf (b,h,t,d) bf16.
// Block: 256 thr = 4 waves; wave owns 16 rows; block covers 64 rows x 16 cols.
// ---------------------------------------------------------------------------
__global__ __launch_bounds__(256) void qk_mfma_kernel(
    const bf16_t* __restrict__ hsbf, const bf16_t* __restrict__ Wbf,
    const float* __restrict__ bias,
    bf16_t* __restrict__ Qbf, bf16_t* __restrict__ Kbf)
{
    const int wave = threadIdx.x >> 6;
    const int lane = threadIdx.x & 63;
    const int lrow = lane & 15;
    const int kgrp = lane >> 4;

    const int c0  = blockIdx.x * 16;
    const int r0w = blockIdx.y * 64 + 16 * wave;

    const bf16_t* arow = hsbf + (size_t)(r0w + lrow) * EE;
    const bf16_t* brow = Wbf  + (size_t)(c0  + lrow) * EE;

    f32x4 acc = {0.f, 0.f, 0.f, 0.f};
    for (int k0 = 0; k0 < EE; k0 += 32) {
        bf16x8 a  = *(const bf16x8*)(arow + k0 + 8 * kgrp);
        bf16x8 bb = *(const bf16x8*)(brow + k0 + 8 * kgrp);
        acc = __builtin_amdgcn_mfma_f32_16x16x32_bf16(a, bb, acc, 0, 0, 0);
    }

#pragma unroll
    for (int r = 0; r < 4; ++r) {
        const int rr = r0w + 4 * kgrp + r;     // output row (b*T+t)
        const int cc = c0 + lrow;              // output col
        const float v = acc[r] + bias[cc];
        const int b = rr >> 11, t = rr & (TT - 1);
        if (cc < EE) {
            Qbf[(size_t)rr * EE + cc] = (__bf16)v;
        } else {
            const int h = (cc - EE) >> 6, d = (cc - EE) & 63;
            Kbf[(((size_t)(b * HH + h)) * TT + t) * DD + d] = (__bf16)v;
        }
    }
}

// ---------------------------------------------------------------------------
// Pass 1: L[b,h,i] = sum_{j<i} exp(0.125 * q_i . k_j)   (no max subtraction;
// |s| <~ 3 so exp is f32-safe; identical normalized result).
// Block: (qtile 64 rows, h, b); 4 waves x 16 rows; loop j tiles of 16.
// ---------------------------------------------------------------------------
__global__ __launch_bounds__(256) void rowsum_kernel(
    const bf16_t* __restrict__ Qbf, const bf16_t* __restrict__ Kbf,
    float* __restrict__ L)
{
    const int wave = threadIdx.x >> 6;
    const int lane = threadIdx.x & 63;
    const int lrow = lane & 15;
    const int kgrp = lane >> 4;

    const int qi0 = blockIdx.x * 64;
    const int h = blockIdx.y, b = blockIdx.z;
    const int rbase = qi0 + 16 * wave;

    const bf16_t* qb = Qbf + (size_t)(b * TT + rbase + lrow) * EE + h * DD;
    bf16x8 a0 = *(const bf16x8*)(qb + 8 * kgrp);
    bf16x8 a1 = *(const bf16x8*)(qb + 32 + 8 * kgrp);

    const bf16_t* Kh = Kbf + ((size_t)(b * HH + h)) * TT * DD;

    f32x4 rs = {0.f, 0.f, 0.f, 0.f};
    for (int j0 = 0; j0 < qi0 + 64; j0 += 16) {
        const bf16_t* kb = Kh + (size_t)(j0 + lrow) * DD;
        bf16x8 b0 = *(const bf16x8*)(kb + 8 * kgrp);
        bf16x8 b1 = *(const bf16x8*)(kb + 32 + 8 * kgrp);
        f32x4 s = {0.f, 0.f, 0.f, 0.f};
        s = __builtin_amdgcn_mfma_f32_16x16x32_bf16(a0, b0, s, 0, 0, 0);
        s = __builtin_amdgcn_mfma_f32_16x16x32_bf16(a1, b1, s, 0, 0, 0);
        const int jj = j0 + lrow;
#pragma unroll
        for (int r = 0; r < 4; ++r) {
            const int ii = rbase + 4 * kgrp + r;
            if (jj < ii) rs[r] += __expf(0.125f * s[r]);
        }
    }
    // reduce across the 16 lanes holding different cols
#pragma unroll
    for (int off = 1; off < 16; off <<= 1) {
#pragma unroll
        for (int r = 0; r < 4; ++r) rs[r] += __shfl_xor(rs[r], off);
    }
    if (lrow == 0) {
#pragma unroll
        for (int r = 0; r < 4; ++r)
            L[((size_t)(b * HH + h)) * TT + rbase + 4 * kgrp + r] = rs[r];
    }
}

// ---------------------------------------------------------------------------
// Pass 2: recompute score tiles (bit-identical MFMA), accumulate
// avg = sum_h exp(s)/ (H * L_h), then z = (clip(avg)+gumbel)/2,
// e2 = exp(z) (z <= ~7.4, f32-safe), store unnormalized e2 + row sums.
// Block: 16 q-rows (qi0), all heads; 4 waves stripe over j tiles of 16.
// ---------------------------------------------------------------------------
__global__ __launch_bounds__(256) void dw_kernel(
    const bf16_t* __restrict__ Qbf, const bf16_t* __restrict__ Kbf,
    const float* __restrict__ L,
    float* __restrict__ dwf, float* __restrict__ rowsum)
{
    __shared__ float invl[HH][16];
    __shared__ float rspart[4][16];

    const int tid  = threadIdx.x;
    const int wave = tid >> 6;
    const int lane = tid & 63;
    const int lrow = lane & 15;
    const int kgrp = lane >> 4;

    const int qi0 = blockIdx.x * 16;
    const int b   = blockIdx.y;

    {   // invl[h][rl] = 1 / (H * L[b,h,qi0+rl])
        const int h = tid >> 4, rl = tid & 15;
        const float lv = L[((size_t)(b * HH + h)) * TT + qi0 + rl];
        invl[h][rl] = (lv > 0.f) ? 1.0f / (lv * (float)HH) : 0.f;
    }
    __syncthreads();

    f32x4 rs = {0.f, 0.f, 0.f, 0.f};

    for (int jt = wave; jt * 16 <= qi0; jt += 4) {
        const int j0 = jt * 16;
        const int jj = j0 + lrow;
        f32x4 avg = {0.f, 0.f, 0.f, 0.f};
#pragma unroll 1
        for (int h = 0; h < HH; ++h) {
            const bf16_t* qb = Qbf + (size_t)(b * TT + qi0 + lrow) * EE + h * DD;
            bf16x8 a0 = *(const bf16x8*)(qb + 8 * kgrp);
            bf16x8 a1 = *(const bf16x8*)(qb + 32 + 8 * kgrp);
            const bf16_t* kb = Kbf + ((size_t)(b * HH + h) * TT + j0 + lrow) * DD;
            bf16x8 b0 = *(const bf16x8*)(kb + 8 * kgrp);
            bf16x8 b1 = *(const bf16x8*)(kb + 32 + 8 * kgrp);
            f32x4 s = {0.f, 0.f, 0.f, 0.f};
            s = __builtin_amdgcn_mfma_f32_16x16x32_bf16(a0, b0, s, 0, 0, 0);
            s = __builtin_amdgcn_mfma_f32_16x16x32_bf16(a1, b1, s, 0, 0, 0);
#pragma unroll
            for (int r = 0; r < 4; ++r) {
                const int iloc = 4 * kgrp + r;
                if (jj < qi0 + iloc)
                    avg[r] += __expf(0.125f * s[r]) * invl[h][iloc];
            }
        }
#pragma unroll
        for (int r = 0; r < 4; ++r) {
            const int iloc = 4 * kgrp + r;
            const int ii = qi0 + iloc;
            if (jj < ii) {
                const float lg = fminf(fmaxf(avg[r], -40.0f), 40.0f);
                const float g = gumbel_for(((unsigned)(b * TT + ii)) * TT + (unsigned)jj);
                const float e2 = __expf((lg + g) * 0.5f);
                rs[r] += e2;
                dwf[(size_t)(b * TT + ii) * TT + jj] = e2;
            }
        }
    }

    // reduce rs across cols (16 lanes), then across waves
#pragma unroll
    for (int off = 1; off < 16; off <<= 1) {
#pragma unroll
        for (int r = 0; r < 4; ++r) rs[r] += __shfl_xor(rs[r], off);
    }
    if (lrow == 0) {
#pragma unroll
        for (int r = 0; r < 4; ++r) rspart[wave][4 * kgrp + r] = rs[r];
    }
    __syncthreads();
    if (tid < 16) {
        const float tot = rspart[0][tid] + rspart[1][tid] +
                          rspart[2][tid] + rspart[3][tid];
        rowsum[b * TT + qi0 + tid] = tot;
    }
}

// ---------------------------------------------------------------------------
// Normalize dw rows in place; zero masked region and row 0.
// ---------------------------------------------------------------------------
__global__ __launch_bounds__(256) void normalize_kernel(
    float* __restrict__ dwf, const float* __restrict__ rowsum)
{
    const int blk = blockIdx.x;            // b*T + i
    const int i = blk & (TT - 1);
    const float rsv = rowsum[blk];
    const float inv = (i > 0 && rsv > 0.f) ? 1.0f / rsv : 0.f;
    float* row = dwf + (size_t)blk * TT;
    for (int j = threadIdx.x; j < TT; j += 256)
        row[j] = (j < i) ? row[j] * inv : 0.f;
}

// ---------------------------------------------------------------------------
// Kernel C: out[b] = dw[b] (TxT) @ hs[b] (TxE)   (f32, unchanged)
// ---------------------------------------------------------------------------
__global__ __launch_bounds__(256) void outgemm_kernel(
    const float* __restrict__ dw, const float* __restrict__ hs,
    float* __restrict__ out)
{
    __shared__ float As[64][17];
    __shared__ float Bs[16][68];

    const int b  = blockIdx.z;
    const int i0 = blockIdx.y * 64;
    const int e0 = blockIdx.x * 64;
    const float* A  = dw + (size_t)b * TT * TT;
    const float* Bm = hs + (size_t)b * TT * EE;
    float* C = out + (size_t)b * TT * EE;

    const int tid = threadIdx.x;
    const int ty = tid >> 4, tx = tid & 15;
    const int lrA = tid >> 2,  lcA = (tid & 3) * 4;
    const int lrB = tid >> 4,  lcB = (tid & 15) * 4;

    float acc[4][4] = {};

    for (int k0 = 0; k0 < TT; k0 += 16) {
        float4 av = *(const float4*)(A + (size_t)(i0 + lrA) * TT + k0 + lcA);
        As[lrA][lcA + 0] = av.x; As[lrA][lcA + 1] = av.y;
        As[lrA][lcA + 2] = av.z; As[lrA][lcA + 3] = av.w;
        float4 bv = *(const float4*)(Bm + (size_t)(k0 + lrB) * EE + e0 + lcB);
        Bs[lrB][lcB + 0] = bv.x; Bs[lrB][lcB + 1] = bv.y;
        Bs[lrB][lcB + 2] = bv.z; Bs[lrB][lcB + 3] = bv.w;
        __syncthreads();
#pragma unroll
        for (int kk = 0; kk < 16; ++kk) {
            float a[4], bb[4];
#pragma unroll
            for (int m = 0; m < 4; ++m) a[m] = As[ty * 4 + m][kk];
#pragma unroll
            for (int n = 0; n < 4; ++n) bb[n] = Bs[kk][tx * 4 + n];
#pragma unroll
            for (int m = 0; m < 4; ++m)
#pragma unroll
                for (int n = 0; n < 4; ++n) acc[m][n] += a[m] * bb[n];
        }
        __syncthreads();
    }

#pragma unroll
    for (int m = 0; m < 4; ++m)
#pragma unroll
        for (int n = 0; n < 4; ++n)
            C[(size_t)(i0 + ty * 4 + m) * EE + e0 + tx * 4 + n] = acc[m][n];
}

// ---------------------------------------------------------------------------
extern "C" void kernel_launch(void* const* d_in, const int* in_sizes, int n_in,
                              void* d_out, int out_size, void* d_ws, size_t ws_size,
                              hipStream_t stream) {
    const float* hs   = (const float*)d_in[0];   // (B,T,E) f32
    const float* W    = (const float*)d_in[1];   // (3E,E)  f32
    const float* bias = (const float*)d_in[2];   // (3E,)   f32
    float* out = (float*)d_out;                  // (B,T,E) f32

    char* ws = (char*)d_ws;
    float*  dwf    = (float*)ws;                                   // 32 MB
    bf16_t* Qbf    = (bf16_t*)(ws + (size_t)32 * 1024 * 1024);     //  8 MB (b,t,e)
    bf16_t* Kbf    = (bf16_t*)(ws + (size_t)40 * 1024 * 1024);     //  8 MB (b,h,t,d)
    bf16_t* hsbf   = (bf16_t*)(ws + (size_t)48 * 1024 * 1024);     //  8 MB
    bf16_t* Wbf    = (bf16_t*)(ws + (size_t)56 * 1024 * 1024);     //  4 MB
    float*  L      = (float*)(ws + (size_t)60 * 1024 * 1024);      // 256 KB
    float*  rowsum = (float*)(ws + (size_t)60 * 1024 * 1024 + 256 * 1024); // 16 KB

    convert_kernel<<<2048, 256, 0, stream>>>(hs, W, hsbf, Wbf);
    qk_mfma_kernel<<<dim3(2048 / 16, 4096 / 64), 256, 0, stream>>>(hsbf, Wbf, bias, Qbf, Kbf);
    rowsum_kernel<<<dim3(TT / 64, HH, BB), 256, 0, stream>>>(Qbf, Kbf, L);
    dw_kernel<<<dim3(TT / 16, BB), 256, 0, stream>>>(Qbf, Kbf, L, dwf, rowsum);
    normalize_kernel<<<BB * TT, 256, 0, stream>>>(dwf, rowsum);
    outgemm_kernel<<<dim3(EE / 64, TT / 64, BB), 256, 0, stream>>>(dwf, hs, out);
}

// Round 5
// 543.562 us; speedup vs baseline: 4.7963x; 1.5974x over previous
//
#include <hip/hip_runtime.h>
#include <math.h>

// Problem constants: B=2, T=2048, E=1024, H=16, D=64
#define TT 2048
#define EE 1024
#define HH 16
#define DD 64
#define BB 2

typedef __bf16 bf16_t;
typedef __attribute__((ext_vector_type(8))) __bf16 bf16x8;
typedef __attribute__((ext_vector_type(4))) float f32x4;

__device__ __forceinline__ unsigned short f2b(float v) {
    return __builtin_bit_cast(unsigned short, (__bf16)v);
}

// ---------------------------------------------------------------------------
// Threefry-2x32, JAX partitionable stream, key=(0,42). Verified round 3.
// ---------------------------------------------------------------------------
__device__ __forceinline__ unsigned int rotl32(unsigned int x, int r) {
    return (x << r) | (x >> (32 - r));
}

__device__ __forceinline__ float gumbel_for(unsigned int f) {
    const unsigned int ks0 = 0u;
    const unsigned int ks1 = 42u;
    const unsigned int ks2 = 0x1BD11BDAu ^ ks0 ^ ks1;

    unsigned int v0 = 0u + ks0;
    unsigned int v1 = f  + ks1;

    v0 += v1; v1 = rotl32(v1, 13); v1 ^= v0;
    v0 += v1; v1 = rotl32(v1, 15); v1 ^= v0;
    v0 += v1; v1 = rotl32(v1, 26); v1 ^= v0;
    v0 += v1; v1 = rotl32(v1,  6); v1 ^= v0;
    v0 += ks1; v1 += ks2 + 1u;
    v0 += v1; v1 = rotl32(v1, 17); v1 ^= v0;
    v0 += v1; v1 = rotl32(v1, 29); v1 ^= v0;
    v0 += v1; v1 = rotl32(v1, 16); v1 ^= v0;
    v0 += v1; v1 = rotl32(v1, 24); v1 ^= v0;
    v0 += ks2; v1 += ks0 + 2u;
    v0 += v1; v1 = rotl32(v1, 13); v1 ^= v0;
    v0 += v1; v1 = rotl32(v1, 15); v1 ^= v0;
    v0 += v1; v1 = rotl32(v1, 26); v1 ^= v0;
    v0 += v1; v1 = rotl32(v1,  6); v1 ^= v0;
    v0 += ks0; v1 += ks1 + 3u;
    v0 += v1; v1 = rotl32(v1, 17); v1 ^= v0;
    v0 += v1; v1 = rotl32(v1, 29); v1 ^= v0;
    v0 += v1; v1 = rotl32(v1, 16); v1 ^= v0;
    v0 += v1; v1 = rotl32(v1, 24); v1 ^= v0;
    v0 += ks1; v1 += ks2 + 4u;
    v0 += v1; v1 = rotl32(v1, 13); v1 ^= v0;
    v0 += v1; v1 = rotl32(v1, 15); v1 ^= v0;
    v0 += v1; v1 = rotl32(v1, 26); v1 ^= v0;
    v0 += v1; v1 = rotl32(v1,  6); v1 ^= v0;
    v0 += ks2; v1 += ks0 + 5u;

    unsigned int bits = v0 ^ v1;
    unsigned int fb = (bits >> 9) | 0x3F800000u;
    float u01 = __uint_as_float(fb) - 1.0f;
    const float mn = 1e-6f;
    const float mx = 1.0f - 1e-6f;
    float u = fmaxf(mn, u01 * (mx - mn) + mn);
    return -__logf(-__logf(u));
}

// ---------------------------------------------------------------------------
// Convert hs (4M f32) and W[0:2048] (2M f32) to bf16.
// ---------------------------------------------------------------------------
__global__ __launch_bounds__(256) void convert_kernel(
    const float* __restrict__ hs, const float* __restrict__ W,
    bf16_t* __restrict__ hsbf, bf16_t* __restrict__ Wbf)
{
    const int n1 = BB * TT * EE / 4;
    const int n2 = 2 * EE * EE / 4;
    const int total = n1 + n2;
    for (int idx = blockIdx.x * 256 + threadIdx.x; idx < total;
         idx += gridDim.x * 256) {
        float4 v = (idx < n1) ? ((const float4*)hs)[idx]
                              : ((const float4*)W)[idx - n1];
        ushort4 o;
        o.x = f2b(v.x); o.y = f2b(v.y); o.z = f2b(v.z); o.w = f2b(v.w);
        if (idx < n1) ((ushort4*)hsbf)[idx] = o;
        else          ((ushort4*)Wbf)[idx - n1] = o;
    }
}

// ---------------------------------------------------------------------------
// Transpose hs -> hsT bf16: hsT[b][e][t] = hs[b][t][e]
// ---------------------------------------------------------------------------
__global__ __launch_bounds__(256) void transpose_kernel(
    const float* __restrict__ hs, bf16_t* __restrict__ hsT)
{
    __shared__ float ts[64][65];
    const int e0 = blockIdx.x * 64;
    const int t0 = blockIdx.y * 64;
    const int b  = blockIdx.z;
    const int tid = threadIdx.x;
#pragma unroll
    for (int it = 0; it < 16; ++it) {
        const int idx = it * 256 + tid;
        const int tr = idx >> 6, te = idx & 63;
        ts[tr][te] = hs[((size_t)(b * TT + t0 + tr)) * EE + e0 + te];
    }
    __syncthreads();
#pragma unroll
    for (int it = 0; it < 16; ++it) {
        const int idx = it * 256 + tid;
        const int er = idx >> 6, tc = idx & 63;
        hsT[((size_t)(b * EE + e0 + er)) * TT + t0 + tc] = (__bf16)ts[tc][er];
    }
}

// ---------------------------------------------------------------------------
// QK projection via MFMA, 64x64 output tiles.
// C[r,c] = hsbf[r,:].Wbf[c,:] + bias[c]; c<1024 -> Qbf(b,t,e); else Kbf(b,h,t,d)
// ---------------------------------------------------------------------------
__global__ __launch_bounds__(256) void qk_mfma_kernel(
    const bf16_t* __restrict__ hsbf, const bf16_t* __restrict__ Wbf,
    const float* __restrict__ bias,
    bf16_t* __restrict__ Qbf, bf16_t* __restrict__ Kbf)
{
    const int wave = threadIdx.x >> 6;
    const int lane = threadIdx.x & 63;
    const int lrow = lane & 15;
    const int kgrp = lane >> 4;

    const int c0 = blockIdx.x * 64;
    const int r0 = blockIdx.y * 64 + 16 * wave;

    const bf16_t* arow = hsbf + (size_t)(r0 + lrow) * EE;

    f32x4 acc[4] = {{0,0,0,0},{0,0,0,0},{0,0,0,0},{0,0,0,0}};
    for (int k0 = 0; k0 < EE; k0 += 32) {
        bf16x8 a = *(const bf16x8*)(arow + k0 + 8 * kgrp);
#pragma unroll
        for (int n = 0; n < 4; ++n) {
            bf16x8 bb = *(const bf16x8*)(Wbf + (size_t)(c0 + 16 * n + lrow) * EE + k0 + 8 * kgrp);
            acc[n] = __builtin_amdgcn_mfma_f32_16x16x32_bf16(a, bb, acc[n], 0, 0, 0);
        }
    }

#pragma unroll
    for (int n = 0; n < 4; ++n) {
        const int cc = c0 + 16 * n + lrow;
        const float bv = bias[cc];
#pragma unroll
        for (int r = 0; r < 4; ++r) {
            const int rr = r0 + 4 * kgrp + r;
            const float v = acc[n][r] + bv;
            const int b = rr >> 11, t = rr & (TT - 1);
            if (cc < EE) {
                Qbf[(size_t)rr * EE + cc] = (__bf16)v;
            } else {
                const int h = (cc - EE) >> 6, d = (cc - EE) & 63;
                Kbf[(((size_t)(b * HH + h)) * TT + t) * DD + d] = (__bf16)v;
            }
        }
    }
}

// ---------------------------------------------------------------------------
// Pass 1: L[b,h,i] = sum_{j<i} exp(0.125*q_i.k_j). Load-balanced: block x
// handles i-tiles x and 31-x (work x+1 + 32-x = const).
// ---------------------------------------------------------------------------
__global__ __launch_bounds__(256) void rowsum_kernel(
    const bf16_t* __restrict__ Qbf, const bf16_t* __restrict__ Kbf,
    float* __restrict__ L)
{
    const int wave = threadIdx.x >> 6;
    const int lane = threadIdx.x & 63;
    const int lrow = lane & 15;
    const int kgrp = lane >> 4;
    const int h = blockIdx.y, b = blockIdx.z;
    const bf16_t* Kh = Kbf + ((size_t)(b * HH + h)) * TT * DD;

#pragma unroll
    for (int pick = 0; pick < 2; ++pick) {
        const int tile = pick ? (31 - blockIdx.x) : blockIdx.x;
        const int qi0 = tile * 64;
        const int rbase = qi0 + 16 * wave;

        const bf16_t* qb = Qbf + (size_t)(b * TT + rbase + lrow) * EE + h * DD;
        bf16x8 a0 = *(const bf16x8*)(qb + 8 * kgrp);
        bf16x8 a1 = *(const bf16x8*)(qb + 32 + 8 * kgrp);

        f32x4 rs = {0.f, 0.f, 0.f, 0.f};
        for (int j0 = 0; j0 < qi0 + 64; j0 += 16) {
            const bf16_t* kb = Kh + (size_t)(j0 + lrow) * DD;
            bf16x8 b0 = *(const bf16x8*)(kb + 8 * kgrp);
            bf16x8 b1 = *(const bf16x8*)(kb + 32 + 8 * kgrp);
            f32x4 s = {0.f, 0.f, 0.f, 0.f};
            s = __builtin_amdgcn_mfma_f32_16x16x32_bf16(a0, b0, s, 0, 0, 0);
            s = __builtin_amdgcn_mfma_f32_16x16x32_bf16(a1, b1, s, 0, 0, 0);
            const int jj = j0 + lrow;
#pragma unroll
            for (int r = 0; r < 4; ++r) {
                const int ii = rbase + 4 * kgrp + r;
                if (jj < ii) rs[r] += __expf(0.125f * s[r]);
            }
        }
#pragma unroll
        for (int off = 1; off < 16; off <<= 1) {
#pragma unroll
            for (int r = 0; r < 4; ++r) rs[r] += __shfl_xor(rs[r], off);
        }
        if (lrow == 0) {
#pragma unroll
            for (int r = 0; r < 4; ++r)
                L[((size_t)(b * HH + h)) * TT + rbase + 4 * kgrp + r] = rs[r];
        }
    }
}

// ---------------------------------------------------------------------------
// Pass 2: independent 32x32 lower-triangle tiles. avg = sum_h exp(s)*invl,
// then z=(clip(avg)+gumbel)/2, write UNNORMALIZED exp(z) as bf16.
// Grid (jt, it, b); jt > it exits.
// ---------------------------------------------------------------------------
__global__ __launch_bounds__(256) void dw_tile_kernel(
    const bf16_t* __restrict__ Qbf, const bf16_t* __restrict__ Kbf,
    const float* __restrict__ L, bf16_t* __restrict__ dwbf)
{
    const int jt = blockIdx.x, it = blockIdx.y, b = blockIdx.z;
    if (jt > it) return;

    __shared__ float invl[HH][32];

    const int tid = threadIdx.x;
    const int i0 = it * 32, j0 = jt * 32;
    {
        const int idx = tid;             // 256 threads cover 512 entries in 2 steps
#pragma unroll
        for (int s = 0; s < 2; ++s) {
            const int e = idx + s * 256;
            const int h = e >> 5, rl = e & 31;
            const float lv = L[((size_t)(b * HH + h)) * TT + i0 + rl];
            invl[h][rl] = (lv > 0.f) ? 1.0f / (lv * (float)HH) : 0.f;
        }
    }
    __syncthreads();

    const int wave = tid >> 6;
    const int lane = tid & 63;
    const int lrow = lane & 15;
    const int kgrp = lane >> 4;
    const int wi = wave >> 1, wj = wave & 1;
    const int ibase = i0 + 16 * wi;
    const int jbase = j0 + 16 * wj;

    if (jbase - ibase >= 16) return;    // fully-masked quadrant (diagonal tile)

    const int jj = jbase + lrow;
    f32x4 avg = {0.f, 0.f, 0.f, 0.f};
#pragma unroll 1
    for (int h = 0; h < HH; ++h) {
        const bf16_t* qb = Qbf + (size_t)(b * TT + ibase + lrow) * EE + h * DD;
        bf16x8 a0 = *(const bf16x8*)(qb + 8 * kgrp);
        bf16x8 a1 = *(const bf16x8*)(qb + 32 + 8 * kgrp);
        const bf16_t* kb = Kbf + ((size_t)(b * HH + h) * TT + jbase + lrow) * DD;
        bf16x8 b0 = *(const bf16x8*)(kb + 8 * kgrp);
        bf16x8 b1 = *(const bf16x8*)(kb + 32 + 8 * kgrp);
        f32x4 s = {0.f, 0.f, 0.f, 0.f};
        s = __builtin_amdgcn_mfma_f32_16x16x32_bf16(a0, b0, s, 0, 0, 0);
        s = __builtin_amdgcn_mfma_f32_16x16x32_bf16(a1, b1, s, 0, 0, 0);
#pragma unroll
        for (int r = 0; r < 4; ++r) {
            const int iloc = 16 * wi + 4 * kgrp + r;
            if (jj < i0 + iloc) avg[r] += __expf(0.125f * s[r]) * invl[h][iloc];
        }
    }
#pragma unroll
    for (int r = 0; r < 4; ++r) {
        const int ii = ibase + 4 * kgrp + r;
        if (jj < ii) {
            const float lg = fminf(fmaxf(avg[r], -40.0f), 40.0f);
            const float g = gumbel_for(((unsigned)(b * TT + ii)) * TT + (unsigned)jj);
            const float e2 = __expf((lg + g) * 0.5f);
            dwbf[(size_t)(b * TT + ii) * TT + jj] = (__bf16)e2;
        }
    }
}

// ---------------------------------------------------------------------------
// Row sum (j<i only) + in-place normalize on bf16; zero masked region.
// ---------------------------------------------------------------------------
__global__ __launch_bounds__(256) void normalize_kernel(bf16_t* __restrict__ dwbf)
{
    __shared__ float red[256];
    const int blk = blockIdx.x;           // b*T + i
    const int i = blk & (TT - 1);
    const int tid = threadIdx.x;
    bf16_t* row = dwbf + (size_t)blk * TT;

    float s = 0.f;
    for (int j = tid; j < TT; j += 256)
        if (j < i) s += (float)row[j];
    red[tid] = s; __syncthreads();
    for (int st = 128; st > 0; st >>= 1) {
        if (tid < st) red[tid] += red[tid + st];
        __syncthreads();
    }
    const float tot = red[0];
    const float inv = (i > 0 && tot > 0.f) ? 1.0f / tot : 0.f;
    for (int j = tid; j < TT; j += 256) {
        const float v = (j < i) ? (float)row[j] * inv : 0.f;
        row[j] = (__bf16)v;
    }
}

// ---------------------------------------------------------------------------
// out[b] = dw[b] (TxT, bf16) @ hs[b] (TxE) via MFMA with hsT (b,e,t) bf16.
// 64x64 tiles, f32 output.
// ---------------------------------------------------------------------------
__global__ __launch_bounds__(256) void outgemm_mfma_kernel(
    const bf16_t* __restrict__ dwbf, const bf16_t* __restrict__ hsT,
    float* __restrict__ out)
{
    const int wave = threadIdx.x >> 6;
    const int lane = threadIdx.x & 63;
    const int lrow = lane & 15;
    const int kgrp = lane >> 4;

    const int e0 = blockIdx.x * 64;
    const int b  = blockIdx.z;
    const int ibase = blockIdx.y * 64 + 16 * wave;

    const bf16_t* arow = dwbf + (size_t)(b * TT + ibase + lrow) * TT;

    f32x4 acc[4] = {{0,0,0,0},{0,0,0,0},{0,0,0,0},{0,0,0,0}};
    for (int k0 = 0; k0 < TT; k0 += 32) {
        bf16x8 a = *(const bf16x8*)(arow + k0 + 8 * kgrp);
#pragma unroll
        for (int n = 0; n < 4; ++n) {
            bf16x8 bb = *(const bf16x8*)(hsT + (size_t)(b * EE + e0 + 16 * n + lrow) * TT + k0 + 8 * kgrp);
            acc[n] = __builtin_amdgcn_mfma_f32_16x16x32_bf16(a, bb, acc[n], 0, 0, 0);
        }
    }

#pragma unroll
    for (int n = 0; n < 4; ++n) {
#pragma unroll
        for (int r = 0; r < 4; ++r) {
            const int rr = ibase + 4 * kgrp + r;
            out[(size_t)(b * TT + rr) * EE + e0 + 16 * n + lrow] = acc[n][r];
        }
    }
}

// ---------------------------------------------------------------------------
extern "C" void kernel_launch(void* const* d_in, const int* in_sizes, int n_in,
                              void* d_out, int out_size, void* d_ws, size_t ws_size,
                              hipStream_t stream) {
    const float* hs   = (const float*)d_in[0];   // (B,T,E) f32
    const float* W    = (const float*)d_in[1];   // (3E,E)  f32
    const float* bias = (const float*)d_in[2];   // (3E,)   f32
    float* out = (float*)d_out;                  // (B,T,E) f32

    char* ws = (char*)d_ws;
    bf16_t* dwbf = (bf16_t*)ws;                                  // 16 MB (b,i,j)
    bf16_t* Qbf  = (bf16_t*)(ws + (size_t)16 * 1024 * 1024);     //  8 MB (b,t,e)
    bf16_t* Kbf  = (bf16_t*)(ws + (size_t)24 * 1024 * 1024);     //  8 MB (b,h,t,d)
    bf16_t* hsbf = (bf16_t*)(ws + (size_t)32 * 1024 * 1024);     //  8 MB
    bf16_t* Wbf  = (bf16_t*)(ws + (size_t)40 * 1024 * 1024);     //  4 MB
    bf16_t* hsT  = (bf16_t*)(ws + (size_t)44 * 1024 * 1024);     //  8 MB (b,e,t)
    float*  L    = (float*) (ws + (size_t)52 * 1024 * 1024);     // 256 KB

    convert_kernel<<<2048, 256, 0, stream>>>(hs, W, hsbf, Wbf);
    transpose_kernel<<<dim3(EE / 64, TT / 64, BB), 256, 0, stream>>>(hs, hsT);
    qk_mfma_kernel<<<dim3(2048 / 64, 4096 / 64), 256, 0, stream>>>(hsbf, Wbf, bias, Qbf, Kbf);
    rowsum_kernel<<<dim3(16, HH, BB), 256, 0, stream>>>(Qbf, Kbf, L);
    dw_tile_kernel<<<dim3(TT / 32, TT / 32, BB), 256, 0, stream>>>(Qbf, Kbf, L, dwbf);
    normalize_kernel<<<BB * TT, 256, 0, stream>>>(dwbf);
    outgemm_mfma_kernel<<<dim3(EE / 64, TT / 64, BB), 256, 0, stream>>>(dwbf, hsT, out);
}

// Round 6
// 476.913 us; speedup vs baseline: 5.4666x; 1.1397x over previous
//
#include <hip/hip_runtime.h>
#include <math.h>

// Problem constants: B=2, T=2048, E=1024, H=16, D=64
#define TT 2048
#define EE 1024
#define HH 16
#define DD 64
#define BB 2

typedef __bf16 bf16_t;
typedef __attribute__((ext_vector_type(8))) __bf16 bf16x8;
typedef __attribute__((ext_vector_type(4))) float f32x4;

__device__ __forceinline__ unsigned short f2b(float v) {
    return __builtin_bit_cast(unsigned short, (__bf16)v);
}

// ---------------------------------------------------------------------------
// Threefry-2x32, JAX partitionable stream, key=(0,42). Verified round 3.
// ---------------------------------------------------------------------------
__device__ __forceinline__ unsigned int rotl32(unsigned int x, int r) {
    return (x << r) | (x >> (32 - r));
}

__device__ __forceinline__ float gumbel_for(unsigned int f) {
    const unsigned int ks0 = 0u;
    const unsigned int ks1 = 42u;
    const unsigned int ks2 = 0x1BD11BDAu ^ ks0 ^ ks1;

    unsigned int v0 = 0u + ks0;
    unsigned int v1 = f  + ks1;

    v0 += v1; v1 = rotl32(v1, 13); v1 ^= v0;
    v0 += v1; v1 = rotl32(v1, 15); v1 ^= v0;
    v0 += v1; v1 = rotl32(v1, 26); v1 ^= v0;
    v0 += v1; v1 = rotl32(v1,  6); v1 ^= v0;
    v0 += ks1; v1 += ks2 + 1u;
    v0 += v1; v1 = rotl32(v1, 17); v1 ^= v0;
    v0 += v1; v1 = rotl32(v1, 29); v1 ^= v0;
    v0 += v1; v1 = rotl32(v1, 16); v1 ^= v0;
    v0 += v1; v1 = rotl32(v1, 24); v1 ^= v0;
    v0 += ks2; v1 += ks0 + 2u;
    v0 += v1; v1 = rotl32(v1, 13); v1 ^= v0;
    v0 += v1; v1 = rotl32(v1, 15); v1 ^= v0;
    v0 += v1; v1 = rotl32(v1, 26); v1 ^= v0;
    v0 += v1; v1 = rotl32(v1,  6); v1 ^= v0;
    v0 += ks0; v1 += ks1 + 3u;
    v0 += v1; v1 = rotl32(v1, 17); v1 ^= v0;
    v0 += v1; v1 = rotl32(v1, 29); v1 ^= v0;
    v0 += v1; v1 = rotl32(v1, 16); v1 ^= v0;
    v0 += v1; v1 = rotl32(v1, 24); v1 ^= v0;
    v0 += ks1; v1 += ks2 + 4u;
    v0 += v1; v1 = rotl32(v1, 13); v1 ^= v0;
    v0 += v1; v1 = rotl32(v1, 15); v1 ^= v0;
    v0 += v1; v1 = rotl32(v1, 26); v1 ^= v0;
    v0 += v1; v1 = rotl32(v1,  6); v1 ^= v0;
    v0 += ks2; v1 += ks0 + 5u;

    unsigned int bits = v0 ^ v1;
    unsigned int fb = (bits >> 9) | 0x3F800000u;
    float u01 = __uint_as_float(fb) - 1.0f;
    const float mn = 1e-6f;
    const float mx = 1.0f - 1e-6f;
    float u = fmaxf(mn, u01 * (mx - mn) + mn);
    return -__logf(-__logf(u));
}

// ---------------------------------------------------------------------------
// Convert hs (4M f32) and W[0:2048] (2M f32) to bf16.
// ---------------------------------------------------------------------------
__global__ __launch_bounds__(256) void convert_kernel(
    const float* __restrict__ hs, const float* __restrict__ W,
    bf16_t* __restrict__ hsbf, bf16_t* __restrict__ Wbf)
{
    const int n1 = BB * TT * EE / 4;
    const int n2 = 2 * EE * EE / 4;
    const int total = n1 + n2;
    for (int idx = blockIdx.x * 256 + threadIdx.x; idx < total;
         idx += gridDim.x * 256) {
        float4 v = (idx < n1) ? ((const float4*)hs)[idx]
                              : ((const float4*)W)[idx - n1];
        ushort4 o;
        o.x = f2b(v.x); o.y = f2b(v.y); o.z = f2b(v.z); o.w = f2b(v.w);
        if (idx < n1) ((ushort4*)hsbf)[idx] = o;
        else          ((ushort4*)Wbf)[idx - n1] = o;
    }
}

// ---------------------------------------------------------------------------
// Transpose hs -> hsT bf16: hsT[b][e][t] = hs[b][t][e]
// ---------------------------------------------------------------------------
__global__ __launch_bounds__(256) void transpose_kernel(
    const float* __restrict__ hs, bf16_t* __restrict__ hsT)
{
    __shared__ float ts[64][65];
    const int e0 = blockIdx.x * 64;
    const int t0 = blockIdx.y * 64;
    const int b  = blockIdx.z;
    const int tid = threadIdx.x;
#pragma unroll
    for (int it = 0; it < 16; ++it) {
        const int idx = it * 256 + tid;
        const int tr = idx >> 6, te = idx & 63;
        ts[tr][te] = hs[((size_t)(b * TT + t0 + tr)) * EE + e0 + te];
    }
    __syncthreads();
#pragma unroll
    for (int it = 0; it < 16; ++it) {
        const int idx = it * 256 + tid;
        const int er = idx >> 6, tc = idx & 63;
        hsT[((size_t)(b * EE + e0 + er)) * TT + t0 + tc] = (__bf16)ts[tc][er];
    }
}

// ---------------------------------------------------------------------------
// QK projection via MFMA, 64x64 output tiles.
// ---------------------------------------------------------------------------
__global__ __launch_bounds__(256) void qk_mfma_kernel(
    const bf16_t* __restrict__ hsbf, const bf16_t* __restrict__ Wbf,
    const float* __restrict__ bias,
    bf16_t* __restrict__ Qbf, bf16_t* __restrict__ Kbf)
{
    const int wave = threadIdx.x >> 6;
    const int lane = threadIdx.x & 63;
    const int lrow = lane & 15;
    const int kgrp = lane >> 4;

    const int c0 = blockIdx.x * 64;
    const int r0 = blockIdx.y * 64 + 16 * wave;

    const bf16_t* arow = hsbf + (size_t)(r0 + lrow) * EE;

    f32x4 acc[4] = {{0,0,0,0},{0,0,0,0},{0,0,0,0},{0,0,0,0}};
    for (int k0 = 0; k0 < EE; k0 += 32) {
        bf16x8 a = *(const bf16x8*)(arow + k0 + 8 * kgrp);
#pragma unroll
        for (int n = 0; n < 4; ++n) {
            bf16x8 bb = *(const bf16x8*)(Wbf + (size_t)(c0 + 16 * n + lrow) * EE + k0 + 8 * kgrp);
            acc[n] = __builtin_amdgcn_mfma_f32_16x16x32_bf16(a, bb, acc[n], 0, 0, 0);
        }
    }

#pragma unroll
    for (int n = 0; n < 4; ++n) {
        const int cc = c0 + 16 * n + lrow;
        const float bv = bias[cc];
#pragma unroll
        for (int r = 0; r < 4; ++r) {
            const int rr = r0 + 4 * kgrp + r;
            const float v = acc[n][r] + bv;
            const int b = rr >> 11, t = rr & (TT - 1);
            if (cc < EE) {
                Qbf[(size_t)rr * EE + cc] = (__bf16)v;
            } else {
                const int h = (cc - EE) >> 6, d = (cc - EE) & 63;
                Kbf[(((size_t)(b * HH + h)) * TT + t) * DD + d] = (__bf16)v;
            }
        }
    }
}

// ---------------------------------------------------------------------------
// Pass 1: L[b,h,i] = sum_{j<i} exp(0.125*q_i.k_j). Block handles i-tiles
// x and 31-x (constant total work).
// ---------------------------------------------------------------------------
__global__ __launch_bounds__(256) void rowsum_kernel(
    const bf16_t* __restrict__ Qbf, const bf16_t* __restrict__ Kbf,
    float* __restrict__ L)
{
    const int wave = threadIdx.x >> 6;
    const int lane = threadIdx.x & 63;
    const int lrow = lane & 15;
    const int kgrp = lane >> 4;
    const int h = blockIdx.y, b = blockIdx.z;
    const bf16_t* Kh = Kbf + ((size_t)(b * HH + h)) * TT * DD;

#pragma unroll
    for (int pick = 0; pick < 2; ++pick) {
        const int tile = pick ? (31 - blockIdx.x) : blockIdx.x;
        const int qi0 = tile * 64;
        const int rbase = qi0 + 16 * wave;

        const bf16_t* qb = Qbf + (size_t)(b * TT + rbase + lrow) * EE + h * DD;
        bf16x8 a0 = *(const bf16x8*)(qb + 8 * kgrp);
        bf16x8 a1 = *(const bf16x8*)(qb + 32 + 8 * kgrp);

        f32x4 rs = {0.f, 0.f, 0.f, 0.f};
        for (int j0 = 0; j0 < qi0 + 64; j0 += 16) {
            const bf16_t* kb = Kh + (size_t)(j0 + lrow) * DD;
            bf16x8 b0 = *(const bf16x8*)(kb + 8 * kgrp);
            bf16x8 b1 = *(const bf16x8*)(kb + 32 + 8 * kgrp);
            f32x4 s = {0.f, 0.f, 0.f, 0.f};
            s = __builtin_amdgcn_mfma_f32_16x16x32_bf16(a0, b0, s, 0, 0, 0);
            s = __builtin_amdgcn_mfma_f32_16x16x32_bf16(a1, b1, s, 0, 0, 0);
            const int jj = j0 + lrow;
#pragma unroll
            for (int r = 0; r < 4; ++r) {
                const int ii = rbase + 4 * kgrp + r;
                if (jj < ii) rs[r] += __expf(0.125f * s[r]);
            }
        }
#pragma unroll
        for (int off = 1; off < 16; off <<= 1) {
#pragma unroll
            for (int r = 0; r < 4; ++r) rs[r] += __shfl_xor(rs[r], off);
        }
        if (lrow == 0) {
#pragma unroll
            for (int r = 0; r < 4; ++r)
                L[((size_t)(b * HH + h)) * TT + rbase + 4 * kgrp + r] = rs[r];
        }
    }
}

// ---------------------------------------------------------------------------
// Pass 2: 64x64 lower-triangle tiles only (triangular grid decode).
// Each wave: 16 i-rows x 64 j-cols = 4 j-frags x 2 k-slices = 8 MFMA/head.
// Writes UNNORMALIZED exp((clip(avg)+gumbel)/2) as bf16 (upper tri left 0
// by the preceding memset).
// ---------------------------------------------------------------------------
__global__ __launch_bounds__(256) void dw_tile_kernel(
    const bf16_t* __restrict__ Qbf, const bf16_t* __restrict__ Kbf,
    const float* __restrict__ L, bf16_t* __restrict__ dwbf)
{
    const int bid = blockIdx.x;
    int it = (int)((sqrtf(8.0f * bid + 1.0f) - 1.0f) * 0.5f);
    while ((it + 1) * (it + 2) / 2 <= bid) ++it;
    while (it * (it + 1) / 2 > bid) --it;
    const int jt = bid - it * (it + 1) / 2;
    const int b = blockIdx.y;

    const int i0 = it * 64, j0 = jt * 64;

    __shared__ float invl[HH][64];
    const int tid = threadIdx.x;
#pragma unroll
    for (int s = 0; s < 4; ++s) {
        const int e = tid + s * 256;
        const int h = e >> 6, rl = e & 63;
        const float lv = L[((size_t)(b * HH + h)) * TT + i0 + rl];
        invl[h][rl] = (lv > 0.f) ? 1.0f / (lv * (float)HH) : 0.f;
    }
    __syncthreads();

    const int wave = tid >> 6;
    const int lane = tid & 63;
    const int lrow = lane & 15;
    const int kgrp = lane >> 4;
    const int ibase = i0 + 16 * wave;
    const int nmax = (it == jt) ? (wave + 1) : 4;

    f32x4 avg[4] = {{0,0,0,0},{0,0,0,0},{0,0,0,0},{0,0,0,0}};

#pragma unroll 2
    for (int h = 0; h < HH; ++h) {
        const bf16_t* qb = Qbf + (size_t)(b * TT + ibase + lrow) * EE + h * DD;
        bf16x8 a0 = *(const bf16x8*)(qb + 8 * kgrp);
        bf16x8 a1 = *(const bf16x8*)(qb + 32 + 8 * kgrp);
        const bf16_t* kbh = Kbf + ((size_t)(b * HH + h) * TT + j0 + lrow) * DD;
#pragma unroll
        for (int n = 0; n < 4; ++n) {
            if (n < nmax) {
                const bf16_t* kb = kbh + (size_t)(16 * n) * DD;
                bf16x8 b0 = *(const bf16x8*)(kb + 8 * kgrp);
                bf16x8 b1 = *(const bf16x8*)(kb + 32 + 8 * kgrp);
                f32x4 s = {0.f, 0.f, 0.f, 0.f};
                s = __builtin_amdgcn_mfma_f32_16x16x32_bf16(a0, b0, s, 0, 0, 0);
                s = __builtin_amdgcn_mfma_f32_16x16x32_bf16(a1, b1, s, 0, 0, 0);
                const int jj = j0 + 16 * n + lrow;
#pragma unroll
                for (int r = 0; r < 4; ++r) {
                    const int iloc = 16 * wave + 4 * kgrp + r;
                    if (jj < i0 + iloc)
                        avg[n][r] += __expf(0.125f * s[r]) * invl[h][iloc];
                }
            }
        }
    }

#pragma unroll
    for (int n = 0; n < 4; ++n) {
        if (n < nmax) {
            const int jj = j0 + 16 * n + lrow;
#pragma unroll
            for (int r = 0; r < 4; ++r) {
                const int ii = ibase + 4 * kgrp + r;
                if (jj < ii) {
                    const float lg = fminf(fmaxf(avg[n][r], -40.0f), 40.0f);
                    const float g = gumbel_for(((unsigned)(b * TT + ii)) * TT + (unsigned)jj);
                    const float e2 = __expf((lg + g) * 0.5f);
                    dwbf[(size_t)(b * TT + ii) * TT + jj] = (__bf16)e2;
                }
            }
        }
    }
}

// ---------------------------------------------------------------------------
// rowinv[b*T+i] = 1 / sum_j dwbf[b,i,j] (upper triangle is 0 via memset).
// ---------------------------------------------------------------------------
__global__ __launch_bounds__(256) void rowinv_kernel(
    const bf16_t* __restrict__ dwbf, float* __restrict__ rowinv)
{
    __shared__ float red[256];
    const int blk = blockIdx.x;           // b*T + i
    const int i = blk & (TT - 1);
    const int tid = threadIdx.x;
    const bf16_t* row = dwbf + (size_t)blk * TT;

    bf16x8 v = *(const bf16x8*)(row + tid * 8);
    float s = 0.f;
#pragma unroll
    for (int e = 0; e < 8; ++e) s += (float)v[e];
    red[tid] = s; __syncthreads();
    for (int st = 128; st > 0; st >>= 1) {
        if (tid < st) red[tid] += red[tid + st];
        __syncthreads();
    }
    if (tid == 0)
        rowinv[blk] = (i > 0 && red[0] > 0.f) ? 1.0f / red[0] : 0.f;
}

// ---------------------------------------------------------------------------
// out[b] = rowinv * (dw[b] (TxT, bf16) @ hs[b]) via MFMA with hsT (b,e,t).
// ---------------------------------------------------------------------------
__global__ __launch_bounds__(256) void outgemm_mfma_kernel(
    const bf16_t* __restrict__ dwbf, const bf16_t* __restrict__ hsT,
    const float* __restrict__ rowinv, float* __restrict__ out)
{
    const int wave = threadIdx.x >> 6;
    const int lane = threadIdx.x & 63;
    const int lrow = lane & 15;
    const int kgrp = lane >> 4;

    const int e0 = blockIdx.x * 64;
    const int b  = blockIdx.z;
    const int ibase = blockIdx.y * 64 + 16 * wave;

    const bf16_t* arow = dwbf + (size_t)(b * TT + ibase + lrow) * TT;

    f32x4 acc[4] = {{0,0,0,0},{0,0,0,0},{0,0,0,0},{0,0,0,0}};
    for (int k0 = 0; k0 < TT; k0 += 32) {
        bf16x8 a = *(const bf16x8*)(arow + k0 + 8 * kgrp);
#pragma unroll
        for (int n = 0; n < 4; ++n) {
            bf16x8 bb = *(const bf16x8*)(hsT + (size_t)(b * EE + e0 + 16 * n + lrow) * TT + k0 + 8 * kgrp);
            acc[n] = __builtin_amdgcn_mfma_f32_16x16x32_bf16(a, bb, acc[n], 0, 0, 0);
        }
    }

    float ri[4];
#pragma unroll
    for (int r = 0; r < 4; ++r) ri[r] = rowinv[b * TT + ibase + 4 * kgrp + r];

#pragma unroll
    for (int n = 0; n < 4; ++n) {
#pragma unroll
        for (int r = 0; r < 4; ++r) {
            const int rr = ibase + 4 * kgrp + r;
            out[(size_t)(b * TT + rr) * EE + e0 + 16 * n + lrow] = acc[n][r] * ri[r];
        }
    }
}

// ---------------------------------------------------------------------------
extern "C" void kernel_launch(void* const* d_in, const int* in_sizes, int n_in,
                              void* d_out, int out_size, void* d_ws, size_t ws_size,
                              hipStream_t stream) {
    const float* hs   = (const float*)d_in[0];   // (B,T,E) f32
    const float* W    = (const float*)d_in[1];   // (3E,E)  f32
    const float* bias = (const float*)d_in[2];   // (3E,)   f32
    float* out = (float*)d_out;                  // (B,T,E) f32

    char* ws = (char*)d_ws;
    bf16_t* dwbf   = (bf16_t*)ws;                                  // 16 MB (b,i,j)
    bf16_t* Qbf    = (bf16_t*)(ws + (size_t)16 * 1024 * 1024);     //  8 MB (b,t,e)
    bf16_t* Kbf    = (bf16_t*)(ws + (size_t)24 * 1024 * 1024);     //  8 MB (b,h,t,d)
    bf16_t* hsbf   = (bf16_t*)(ws + (size_t)32 * 1024 * 1024);     //  8 MB
    bf16_t* Wbf    = (bf16_t*)(ws + (size_t)40 * 1024 * 1024);     //  4 MB
    bf16_t* hsT    = (bf16_t*)(ws + (size_t)44 * 1024 * 1024);     //  8 MB (b,e,t)
    float*  L      = (float*) (ws + (size_t)52 * 1024 * 1024);     // 256 KB
    float*  rowinv = (float*) (ws + (size_t)52 * 1024 * 1024 + 256 * 1024); // 16 KB

    hipMemsetAsync(dwbf, 0, (size_t)16 * 1024 * 1024, stream);
    convert_kernel<<<2048, 256, 0, stream>>>(hs, W, hsbf, Wbf);
    transpose_kernel<<<dim3(EE / 64, TT / 64, BB), 256, 0, stream>>>(hs, hsT);
    qk_mfma_kernel<<<dim3(2048 / 64, 4096 / 64), 256, 0, stream>>>(hsbf, Wbf, bias, Qbf, Kbf);
    rowsum_kernel<<<dim3(16, HH, BB), 256, 0, stream>>>(Qbf, Kbf, L);
    dw_tile_kernel<<<dim3(528, BB), 256, 0, stream>>>(Qbf, Kbf, L, dwbf);
    rowinv_kernel<<<BB * TT, 256, 0, stream>>>(dwbf, rowinv);
    outgemm_mfma_kernel<<<dim3(EE / 64, TT / 64, BB), 256, 0, stream>>>(dwbf, hsT, rowinv, out);
}

// Round 7
// 254.628 us; speedup vs baseline: 10.2389x; 1.8730x over previous
//
#include <hip/hip_runtime.h>
#include <math.h>

// Problem constants: B=2, T=2048, E=1024, H=16, D=64
#define TT 2048
#define EE 1024
#define HH 16
#define DD 64
#define BB 2

typedef __bf16 bf16_t;
typedef __attribute__((ext_vector_type(8))) __bf16 bf16x8;
typedef __attribute__((ext_vector_type(4))) float f32x4;

__device__ __forceinline__ unsigned short f2b(float v) {
    return __builtin_bit_cast(unsigned short, (__bf16)v);
}

// async global->LDS, 16B per lane; LDS dest = wave-uniform base + lane*16
__device__ __forceinline__ void gll16(const void* g, void* l) {
    __builtin_amdgcn_global_load_lds(
        (const __attribute__((address_space(1))) void*)g,
        (__attribute__((address_space(3))) void*)l, 16, 0, 0);
}

// ---------------------------------------------------------------------------
// Threefry-2x32, JAX partitionable stream, key=(0,42). Verified round 3.
// ---------------------------------------------------------------------------
__device__ __forceinline__ unsigned int rotl32(unsigned int x, int r) {
    return (x << r) | (x >> (32 - r));
}

__device__ __forceinline__ float gumbel_for(unsigned int f) {
    const unsigned int ks0 = 0u;
    const unsigned int ks1 = 42u;
    const unsigned int ks2 = 0x1BD11BDAu ^ ks0 ^ ks1;

    unsigned int v0 = 0u + ks0;
    unsigned int v1 = f  + ks1;

    v0 += v1; v1 = rotl32(v1, 13); v1 ^= v0;
    v0 += v1; v1 = rotl32(v1, 15); v1 ^= v0;
    v0 += v1; v1 = rotl32(v1, 26); v1 ^= v0;
    v0 += v1; v1 = rotl32(v1,  6); v1 ^= v0;
    v0 += ks1; v1 += ks2 + 1u;
    v0 += v1; v1 = rotl32(v1, 17); v1 ^= v0;
    v0 += v1; v1 = rotl32(v1, 29); v1 ^= v0;
    v0 += v1; v1 = rotl32(v1, 16); v1 ^= v0;
    v0 += v1; v1 = rotl32(v1, 24); v1 ^= v0;
    v0 += ks2; v1 += ks0 + 2u;
    v0 += v1; v1 = rotl32(v1, 13); v1 ^= v0;
    v0 += v1; v1 = rotl32(v1, 15); v1 ^= v0;
    v0 += v1; v1 = rotl32(v1, 26); v1 ^= v0;
    v0 += v1; v1 = rotl32(v1,  6); v1 ^= v0;
    v0 += ks0; v1 += ks1 + 3u;
    v0 += v1; v1 = rotl32(v1, 17); v1 ^= v0;
    v0 += v1; v1 = rotl32(v1, 29); v1 ^= v0;
    v0 += v1; v1 = rotl32(v1, 16); v1 ^= v0;
    v0 += v1; v1 = rotl32(v1, 24); v1 ^= v0;
    v0 += ks1; v1 += ks2 + 4u;
    v0 += v1; v1 = rotl32(v1, 13); v1 ^= v0;
    v0 += v1; v1 = rotl32(v1, 15); v1 ^= v0;
    v0 += v1; v1 = rotl32(v1, 26); v1 ^= v0;
    v0 += v1; v1 = rotl32(v1,  6); v1 ^= v0;
    v0 += ks2; v1 += ks0 + 5u;

    unsigned int bits = v0 ^ v1;
    unsigned int fb = (bits >> 9) | 0x3F800000u;
    float u01 = __uint_as_float(fb) - 1.0f;
    const float mn = 1e-6f;
    const float mx = 1.0f - 1e-6f;
    float u = fmaxf(mn, u01 * (mx - mn) + mn);
    return -__logf(-__logf(u));
}

// ---------------------------------------------------------------------------
// Convert hs (4M f32) and W[0:2048] (2M f32) to bf16.
// ---------------------------------------------------------------------------
__global__ __launch_bounds__(256) void convert_kernel(
    const float* __restrict__ hs, const float* __restrict__ W,
    bf16_t* __restrict__ hsbf, bf16_t* __restrict__ Wbf)
{
    const int n1 = BB * TT * EE / 4;
    const int n2 = 2 * EE * EE / 4;
    const int total = n1 + n2;
    for (int idx = blockIdx.x * 256 + threadIdx.x; idx < total;
         idx += gridDim.x * 256) {
        float4 v = (idx < n1) ? ((const float4*)hs)[idx]
                              : ((const float4*)W)[idx - n1];
        ushort4 o;
        o.x = f2b(v.x); o.y = f2b(v.y); o.z = f2b(v.z); o.w = f2b(v.w);
        if (idx < n1) ((ushort4*)hsbf)[idx] = o;
        else          ((ushort4*)Wbf)[idx - n1] = o;
    }
}

// ---------------------------------------------------------------------------
// Transpose hs -> hsT bf16: hsT[b][e][t] = hs[b][t][e]
// ---------------------------------------------------------------------------
__global__ __launch_bounds__(256) void transpose_kernel(
    const float* __restrict__ hs, bf16_t* __restrict__ hsT)
{
    __shared__ float ts[64][65];
    const int e0 = blockIdx.x * 64;
    const int t0 = blockIdx.y * 64;
    const int b  = blockIdx.z;
    const int tid = threadIdx.x;
#pragma unroll
    for (int it = 0; it < 16; ++it) {
        const int idx = it * 256 + tid;
        const int tr = idx >> 6, te = idx & 63;
        ts[tr][te] = hs[((size_t)(b * TT + t0 + tr)) * EE + e0 + te];
    }
    __syncthreads();
#pragma unroll
    for (int it = 0; it < 16; ++it) {
        const int idx = it * 256 + tid;
        const int er = idx >> 6, tc = idx & 63;
        hsT[((size_t)(b * EE + e0 + er)) * TT + t0 + tc] = (__bf16)ts[tc][er];
    }
}

// ---------------------------------------------------------------------------
// Shared 128x128-tile GEMM main loop (m97 structure): C = A[M,K] . B[N,K]^T.
// LDS double-buffered via global_load_lds (linear dest, BK=32), 4 waves in
// 2x2, each wave 64x64 (4x4 frags of 16x16x32 MFMA). K/32 must be even.
// ---------------------------------------------------------------------------
template <int K>
__device__ __forceinline__ void gemm_mainloop(
    const bf16_t* __restrict__ A, const bf16_t* __restrict__ Bm,
    int row0, int col0, int wave, int lane,
    bf16_t* Al0, bf16_t* Al1, bf16_t* Bl0, bf16_t* Bl1,
    f32x4 (&acc)[4][4])
{
    const int lrow = lane & 15;
    const int kgrp = lane >> 4;
    const int wr = wave >> 1, wc = wave & 1;
    const int lr4 = lane >> 2;        // staging row within 16
    const int sc  = (lane & 3) * 8;   // staging col (elements)

    auto stage = [&](bf16_t* Ald, bf16_t* Bld, int k0) {
#pragma unroll
        for (int c = 0; c < 2; ++c) {
            const int srow = c * 64 + wave * 16;
            gll16(A  + (size_t)(row0 + srow + lr4) * K + k0 + sc, Ald + srow * 32);
            gll16(Bm + (size_t)(col0 + srow + lr4) * K + k0 + sc, Bld + srow * 32);
        }
    };
    auto compute = [&](const bf16_t* Ald, const bf16_t* Bld) {
        bf16x8 af[4], bfr[4];
#pragma unroll
        for (int m = 0; m < 4; ++m)
            af[m] = *(const bf16x8*)(Ald + (wr * 64 + m * 16 + lrow) * 32 + kgrp * 8);
#pragma unroll
        for (int n = 0; n < 4; ++n)
            bfr[n] = *(const bf16x8*)(Bld + (wc * 64 + n * 16 + lrow) * 32 + kgrp * 8);
#pragma unroll
        for (int m = 0; m < 4; ++m)
#pragma unroll
            for (int n = 0; n < 4; ++n)
                acc[m][n] = __builtin_amdgcn_mfma_f32_16x16x32_bf16(
                    af[m], bfr[n], acc[m][n], 0, 0, 0);
    };

    stage(Al0, Bl0, 0);
    __syncthreads();
#pragma unroll 1
    for (int t = 0; t < K / 32; t += 2) {
        stage(Al1, Bl1, (t + 1) * 32);
        compute(Al0, Bl0);
        __syncthreads();
        if (t + 2 < K / 32) stage(Al0, Bl0, (t + 2) * 32);
        compute(Al1, Bl1);
        __syncthreads();
    }
}

// ---------------------------------------------------------------------------
// QK projection: C[r,c] = hsbf[r,:].Wbf[c,:] + bias[c]; c<1024 -> Qbf(b,t,e),
// else Kbf(b,h,t,d).
// ---------------------------------------------------------------------------
__global__ __launch_bounds__(256) void qk_gemm_kernel(
    const bf16_t* __restrict__ hsbf, const bf16_t* __restrict__ Wbf,
    const float* __restrict__ bias,
    bf16_t* __restrict__ Qbf, bf16_t* __restrict__ Kbf)
{
    __shared__ alignas(16) bf16_t Al0[128 * 32], Al1[128 * 32];
    __shared__ alignas(16) bf16_t Bl0[128 * 32], Bl1[128 * 32];

    const int wave = threadIdx.x >> 6;
    const int lane = threadIdx.x & 63;
    const int lrow = lane & 15;
    const int kgrp = lane >> 4;
    const int wr = wave >> 1, wc = wave & 1;
    const int row0 = blockIdx.y * 128;
    const int col0 = blockIdx.x * 128;

    f32x4 acc[4][4] = {};
    gemm_mainloop<EE>(hsbf, Wbf, row0, col0, wave, lane, Al0, Al1, Bl0, Bl1, acc);

#pragma unroll
    for (int n = 0; n < 4; ++n) {
        const int cc = col0 + wc * 64 + n * 16 + lrow;
        const float bv = bias[cc];
#pragma unroll
        for (int m = 0; m < 4; ++m) {
#pragma unroll
            for (int r = 0; r < 4; ++r) {
                const int rr = row0 + wr * 64 + m * 16 + 4 * kgrp + r;
                const float v = acc[m][n][r] + bv;
                const int b = rr >> 11, t = rr & (TT - 1);
                if (cc < EE) {
                    Qbf[(size_t)rr * EE + cc] = (__bf16)v;
                } else {
                    const int h = (cc - EE) >> 6, d = (cc - EE) & 63;
                    Kbf[(((size_t)(b * HH + h)) * TT + t) * DD + d] = (__bf16)v;
                }
            }
        }
    }
}

// ---------------------------------------------------------------------------
// out[b] = rowinv * (dw[b] (TxT bf16) @ hs[b]) with hsT (b,e,t) as B^T.
// ---------------------------------------------------------------------------
__global__ __launch_bounds__(256) void out_gemm_kernel(
    const bf16_t* __restrict__ dwbf, const bf16_t* __restrict__ hsT,
    const float* __restrict__ rowinv, float* __restrict__ out)
{
    __shared__ alignas(16) bf16_t Al0[128 * 32], Al1[128 * 32];
    __shared__ alignas(16) bf16_t Bl0[128 * 32], Bl1[128 * 32];

    const int wave = threadIdx.x >> 6;
    const int lane = threadIdx.x & 63;
    const int lrow = lane & 15;
    const int kgrp = lane >> 4;
    const int wr = wave >> 1, wc = wave & 1;
    const int b = blockIdx.z;
    const int row0 = blockIdx.y * 128;   // within [0,T)
    const int col0 = blockIdx.x * 128;   // within [0,E)

    const bf16_t* A  = dwbf + (size_t)b * TT * TT;
    const bf16_t* Bm = hsT  + (size_t)b * EE * TT;

    f32x4 acc[4][4] = {};
    gemm_mainloop<TT>(A, Bm, row0, col0, wave, lane, Al0, Al1, Bl0, Bl1, acc);

    float ri[4][4];
#pragma unroll
    for (int m = 0; m < 4; ++m)
#pragma unroll
        for (int r = 0; r < 4; ++r)
            ri[m][r] = rowinv[b * TT + row0 + wr * 64 + m * 16 + 4 * kgrp + r];

#pragma unroll
    for (int n = 0; n < 4; ++n) {
        const int cc = col0 + wc * 64 + n * 16 + lrow;
#pragma unroll
        for (int m = 0; m < 4; ++m) {
#pragma unroll
            for (int r = 0; r < 4; ++r) {
                const int rr = row0 + wr * 64 + m * 16 + 4 * kgrp + r;
                out[(size_t)(b * TT + rr) * EE + cc] = acc[m][n][r] * ri[m][r];
            }
        }
    }
}

// ---------------------------------------------------------------------------
// Pass 1: L[b,h,i] = sum_{j<i} exp(0.125*q_i.k_j). Block handles i-tiles
// x and 31-x (constant total work).
// ---------------------------------------------------------------------------
__global__ __launch_bounds__(256) void rowsum_kernel(
    const bf16_t* __restrict__ Qbf, const bf16_t* __restrict__ Kbf,
    float* __restrict__ L)
{
    const int wave = threadIdx.x >> 6;
    const int lane = threadIdx.x & 63;
    const int lrow = lane & 15;
    const int kgrp = lane >> 4;
    const int h = blockIdx.y, b = blockIdx.z;
    const bf16_t* Kh = Kbf + ((size_t)(b * HH + h)) * TT * DD;

#pragma unroll
    for (int pick = 0; pick < 2; ++pick) {
        const int tile = pick ? (31 - blockIdx.x) : blockIdx.x;
        const int qi0 = tile * 64;
        const int rbase = qi0 + 16 * wave;

        const bf16_t* qb = Qbf + (size_t)(b * TT + rbase + lrow) * EE + h * DD;
        bf16x8 a0 = *(const bf16x8*)(qb + 8 * kgrp);
        bf16x8 a1 = *(const bf16x8*)(qb + 32 + 8 * kgrp);

        f32x4 rs = {0.f, 0.f, 0.f, 0.f};
        for (int j0 = 0; j0 < qi0 + 64; j0 += 16) {
            const bf16_t* kb = Kh + (size_t)(j0 + lrow) * DD;
            bf16x8 b0 = *(const bf16x8*)(kb + 8 * kgrp);
            bf16x8 b1 = *(const bf16x8*)(kb + 32 + 8 * kgrp);
            f32x4 s = {0.f, 0.f, 0.f, 0.f};
            s = __builtin_amdgcn_mfma_f32_16x16x32_bf16(a0, b0, s, 0, 0, 0);
            s = __builtin_amdgcn_mfma_f32_16x16x32_bf16(a1, b1, s, 0, 0, 0);
            const int jj = j0 + lrow;
#pragma unroll
            for (int r = 0; r < 4; ++r) {
                const int ii = rbase + 4 * kgrp + r;
                if (jj < ii) rs[r] += __expf(0.125f * s[r]);
            }
        }
#pragma unroll
        for (int off = 1; off < 16; off <<= 1) {
#pragma unroll
            for (int r = 0; r < 4; ++r) rs[r] += __shfl_xor(rs[r], off);
        }
        if (lrow == 0) {
#pragma unroll
            for (int r = 0; r < 4; ++r)
                L[((size_t)(b * HH + h)) * TT + rbase + 4 * kgrp + r] = rs[r];
        }
    }
}

// ---------------------------------------------------------------------------
// Pass 2: 64x64 lower-triangle tiles only (triangular grid decode).
// Writes UNNORMALIZED exp((clip(avg)+gumbel)/2) as bf16.
// ---------------------------------------------------------------------------
__global__ __launch_bounds__(256) void dw_tile_kernel(
    const bf16_t* __restrict__ Qbf, const bf16_t* __restrict__ Kbf,
    const float* __restrict__ L, bf16_t* __restrict__ dwbf)
{
    const int bid = blockIdx.x;
    int it = (int)((sqrtf(8.0f * bid + 1.0f) - 1.0f) * 0.5f);
    while ((it + 1) * (it + 2) / 2 <= bid) ++it;
    while (it * (it + 1) / 2 > bid) --it;
    const int jt = bid - it * (it + 1) / 2;
    const int b = blockIdx.y;

    const int i0 = it * 64, j0 = jt * 64;

    __shared__ float invl[HH][64];
    const int tid = threadIdx.x;
#pragma unroll
    for (int s = 0; s < 4; ++s) {
        const int e = tid + s * 256;
        const int h = e >> 6, rl = e & 63;
        const float lv = L[((size_t)(b * HH + h)) * TT + i0 + rl];
        invl[h][rl] = (lv > 0.f) ? 1.0f / (lv * (float)HH) : 0.f;
    }
    __syncthreads();

    const int wave = tid >> 6;
    const int lane = tid & 63;
    const int lrow = lane & 15;
    const int kgrp = lane >> 4;
    const int ibase = i0 + 16 * wave;
    const int nmax = (it == jt) ? (wave + 1) : 4;

    f32x4 avg[4] = {{0,0,0,0},{0,0,0,0},{0,0,0,0},{0,0,0,0}};

#pragma unroll 2
    for (int h = 0; h < HH; ++h) {
        const bf16_t* qb = Qbf + (size_t)(b * TT + ibase + lrow) * EE + h * DD;
        bf16x8 a0 = *(const bf16x8*)(qb + 8 * kgrp);
        bf16x8 a1 = *(const bf16x8*)(qb + 32 + 8 * kgrp);
        const bf16_t* kbh = Kbf + ((size_t)(b * HH + h) * TT + j0 + lrow) * DD;
#pragma unroll
        for (int n = 0; n < 4; ++n) {
            if (n < nmax) {
                const bf16_t* kb = kbh + (size_t)(16 * n) * DD;
                bf16x8 b0 = *(const bf16x8*)(kb + 8 * kgrp);
                bf16x8 b1 = *(const bf16x8*)(kb + 32 + 8 * kgrp);
                f32x4 s = {0.f, 0.f, 0.f, 0.f};
                s = __builtin_amdgcn_mfma_f32_16x16x32_bf16(a0, b0, s, 0, 0, 0);
                s = __builtin_amdgcn_mfma_f32_16x16x32_bf16(a1, b1, s, 0, 0, 0);
                const int jj = j0 + 16 * n + lrow;
#pragma unroll
                for (int r = 0; r < 4; ++r) {
                    const int iloc = 16 * wave + 4 * kgrp + r;
                    if (jj < i0 + iloc)
                        avg[n][r] += __expf(0.125f * s[r]) * invl[h][iloc];
                }
            }
        }
    }

#pragma unroll
    for (int n = 0; n < 4; ++n) {
        if (n < nmax) {
            const int jj = j0 + 16 * n + lrow;
#pragma unroll
            for (int r = 0; r < 4; ++r) {
                const int ii = ibase + 4 * kgrp + r;
                if (jj < ii) {
                    const float lg = fminf(fmaxf(avg[n][r], -40.0f), 40.0f);
                    const float g = gumbel_for(((unsigned)(b * TT + ii)) * TT + (unsigned)jj);
                    const float e2 = __expf((lg + g) * 0.5f);
                    dwbf[(size_t)(b * TT + ii) * TT + jj] = (__bf16)e2;
                }
            }
        }
    }
}

// ---------------------------------------------------------------------------
// rowinv[b*T+i] = 1 / sum_j dwbf[b,i,j] (upper triangle is 0 via memset).
// ---------------------------------------------------------------------------
__global__ __launch_bounds__(256) void rowinv_kernel(
    const bf16_t* __restrict__ dwbf, float* __restrict__ rowinv)
{
    __shared__ float red[256];
    const int blk = blockIdx.x;           // b*T + i
    const int i = blk & (TT - 1);
    const int tid = threadIdx.x;
    const bf16_t* row = dwbf + (size_t)blk * TT;

    bf16x8 v = *(const bf16x8*)(row + tid * 8);
    float s = 0.f;
#pragma unroll
    for (int e = 0; e < 8; ++e) s += (float)v[e];
    red[tid] = s; __syncthreads();
    for (int st = 128; st > 0; st >>= 1) {
        if (tid < st) red[tid] += red[tid + st];
        __syncthreads();
    }
    if (tid == 0)
        rowinv[blk] = (i > 0 && red[0] > 0.f) ? 1.0f / red[0] : 0.f;
}

// ---------------------------------------------------------------------------
extern "C" void kernel_launch(void* const* d_in, const int* in_sizes, int n_in,
                              void* d_out, int out_size, void* d_ws, size_t ws_size,
                              hipStream_t stream) {
    const float* hs   = (const float*)d_in[0];   // (B,T,E) f32
    const float* W    = (const float*)d_in[1];   // (3E,E)  f32
    const float* bias = (const float*)d_in[2];   // (3E,)   f32
    float* out = (float*)d_out;                  // (B,T,E) f32

    char* ws = (char*)d_ws;
    bf16_t* dwbf   = (bf16_t*)ws;                                  // 16 MB (b,i,j)
    bf16_t* Qbf    = (bf16_t*)(ws + (size_t)16 * 1024 * 1024);     //  8 MB (b,t,e)
    bf16_t* Kbf    = (bf16_t*)(ws + (size_t)24 * 1024 * 1024);     //  8 MB (b,h,t,d)
    bf16_t* hsbf   = (bf16_t*)(ws + (size_t)32 * 1024 * 1024);     //  8 MB
    bf16_t* Wbf    = (bf16_t*)(ws + (size_t)40 * 1024 * 1024);     //  4 MB
    bf16_t* hsT    = (bf16_t*)(ws + (size_t)44 * 1024 * 1024);     //  8 MB (b,e,t)
    float*  L      = (float*) (ws + (size_t)52 * 1024 * 1024);     // 256 KB
    float*  rowinv = (float*) (ws + (size_t)52 * 1024 * 1024 + 256 * 1024); // 16 KB

    hipMemsetAsync(dwbf, 0, (size_t)16 * 1024 * 1024, stream);
    convert_kernel<<<2048, 256, 0, stream>>>(hs, W, hsbf, Wbf);
    transpose_kernel<<<dim3(EE / 64, TT / 64, BB), 256, 0, stream>>>(hs, hsT);
    qk_gemm_kernel<<<dim3(2048 / 128, 4096 / 128), 256, 0, stream>>>(hsbf, Wbf, bias, Qbf, Kbf);
    rowsum_kernel<<<dim3(16, HH, BB), 256, 0, stream>>>(Qbf, Kbf, L);
    dw_tile_kernel<<<dim3(528, BB), 256, 0, stream>>>(Qbf, Kbf, L, dwbf);
    rowinv_kernel<<<BB * TT, 256, 0, stream>>>(dwbf, rowinv);
    out_gemm_kernel<<<dim3(EE / 128, TT / 128, BB), 256, 0, stream>>>(dwbf, hsT, rowinv, out);
}

// Round 8
// 219.019 us; speedup vs baseline: 11.9035x; 1.1626x over previous
//
#include <hip/hip_runtime.h>
#include <math.h>

// Problem constants: B=2, T=2048, E=1024, H=16, D=64
#define TT 2048
#define EE 1024
#define HH 16
#define DD 64
#define BB 2

typedef __bf16 bf16_t;
typedef __attribute__((ext_vector_type(8))) __bf16 bf16x8;
typedef __attribute__((ext_vector_type(4))) float f32x4;

__device__ __forceinline__ unsigned short f2b(float v) {
    return __builtin_bit_cast(unsigned short, (__bf16)v);
}

// async global->LDS, 16B per lane; LDS dest = wave-uniform base + lane*16
__device__ __forceinline__ void gll16(const void* g, void* l) {
    __builtin_amdgcn_global_load_lds(
        (const __attribute__((address_space(1))) void*)g,
        (__attribute__((address_space(3))) void*)l, 16, 0, 0);
}

// ---------------------------------------------------------------------------
// Threefry-2x32, JAX partitionable stream, key=(0,42). Verified round 3.
// ---------------------------------------------------------------------------
__device__ __forceinline__ unsigned int rotl32(unsigned int x, int r) {
    return (x << r) | (x >> (32 - r));
}

__device__ __forceinline__ float gumbel_for(unsigned int f) {
    const unsigned int ks0 = 0u;
    const unsigned int ks1 = 42u;
    const unsigned int ks2 = 0x1BD11BDAu ^ ks0 ^ ks1;

    unsigned int v0 = 0u + ks0;
    unsigned int v1 = f  + ks1;

    v0 += v1; v1 = rotl32(v1, 13); v1 ^= v0;
    v0 += v1; v1 = rotl32(v1, 15); v1 ^= v0;
    v0 += v1; v1 = rotl32(v1, 26); v1 ^= v0;
    v0 += v1; v1 = rotl32(v1,  6); v1 ^= v0;
    v0 += ks1; v1 += ks2 + 1u;
    v0 += v1; v1 = rotl32(v1, 17); v1 ^= v0;
    v0 += v1; v1 = rotl32(v1, 29); v1 ^= v0;
    v0 += v1; v1 = rotl32(v1, 16); v1 ^= v0;
    v0 += v1; v1 = rotl32(v1, 24); v1 ^= v0;
    v0 += ks2; v1 += ks0 + 2u;
    v0 += v1; v1 = rotl32(v1, 13); v1 ^= v0;
    v0 += v1; v1 = rotl32(v1, 15); v1 ^= v0;
    v0 += v1; v1 = rotl32(v1, 26); v1 ^= v0;
    v0 += v1; v1 = rotl32(v1,  6); v1 ^= v0;
    v0 += ks0; v1 += ks1 + 3u;
    v0 += v1; v1 = rotl32(v1, 17); v1 ^= v0;
    v0 += v1; v1 = rotl32(v1, 29); v1 ^= v0;
    v0 += v1; v1 = rotl32(v1, 16); v1 ^= v0;
    v0 += v1; v1 = rotl32(v1, 24); v1 ^= v0;
    v0 += ks1; v1 += ks2 + 4u;
    v0 += v1; v1 = rotl32(v1, 13); v1 ^= v0;
    v0 += v1; v1 = rotl32(v1, 15); v1 ^= v0;
    v0 += v1; v1 = rotl32(v1, 26); v1 ^= v0;
    v0 += v1; v1 = rotl32(v1,  6); v1 ^= v0;
    v0 += ks2; v1 += ks0 + 5u;

    unsigned int bits = v0 ^ v1;
    unsigned int fb = (bits >> 9) | 0x3F800000u;
    float u01 = __uint_as_float(fb) - 1.0f;
    const float mn = 1e-6f;
    const float mx = 1.0f - 1e-6f;
    float u = fmaxf(mn, u01 * (mx - mn) + mn);
    return -__logf(-__logf(u));
}

// ---------------------------------------------------------------------------
// Convert hs (4M f32) and W[0:2048] (2M f32) to bf16.
// ---------------------------------------------------------------------------
__global__ __launch_bounds__(256) void convert_kernel(
    const float* __restrict__ hs, const float* __restrict__ W,
    bf16_t* __restrict__ hsbf, bf16_t* __restrict__ Wbf)
{
    const int n1 = BB * TT * EE / 4;
    const int n2 = 2 * EE * EE / 4;
    const int total = n1 + n2;
    for (int idx = blockIdx.x * 256 + threadIdx.x; idx < total;
         idx += gridDim.x * 256) {
        float4 v = (idx < n1) ? ((const float4*)hs)[idx]
                              : ((const float4*)W)[idx - n1];
        ushort4 o;
        o.x = f2b(v.x); o.y = f2b(v.y); o.z = f2b(v.z); o.w = f2b(v.w);
        if (idx < n1) ((ushort4*)hsbf)[idx] = o;
        else          ((ushort4*)Wbf)[idx - n1] = o;
    }
}

// ---------------------------------------------------------------------------
// Transpose hs -> hsT bf16: hsT[b][e][t] = hs[b][t][e]
// ---------------------------------------------------------------------------
__global__ __launch_bounds__(256) void transpose_kernel(
    const float* __restrict__ hs, bf16_t* __restrict__ hsT)
{
    __shared__ float ts[64][65];
    const int e0 = blockIdx.x * 64;
    const int t0 = blockIdx.y * 64;
    const int b  = blockIdx.z;
    const int tid = threadIdx.x;
#pragma unroll
    for (int it = 0; it < 16; ++it) {
        const int idx = it * 256 + tid;
        const int tr = idx >> 6, te = idx & 63;
        ts[tr][te] = hs[((size_t)(b * TT + t0 + tr)) * EE + e0 + te];
    }
    __syncthreads();
#pragma unroll
    for (int it = 0; it < 16; ++it) {
        const int idx = it * 256 + tid;
        const int er = idx >> 6, tc = idx & 63;
        hsT[((size_t)(b * EE + e0 + er)) * TT + t0 + tc] = (__bf16)ts[tc][er];
    }
}

// ---------------------------------------------------------------------------
// Shared 128x128-tile GEMM main loop (m97 structure): C = A[M,K] . B[N,K]^T.
// ---------------------------------------------------------------------------
template <int K>
__device__ __forceinline__ void gemm_mainloop(
    const bf16_t* __restrict__ A, const bf16_t* __restrict__ Bm,
    int row0, int col0, int wave, int lane,
    bf16_t* Al0, bf16_t* Al1, bf16_t* Bl0, bf16_t* Bl1,
    f32x4 (&acc)[4][4])
{
    const int lrow = lane & 15;
    const int kgrp = lane >> 4;
    const int wr = wave >> 1, wc = wave & 1;
    const int lr4 = lane >> 2;        // staging row within 16
    const int sc  = (lane & 3) * 8;   // staging col (elements)

    auto stage = [&](bf16_t* Ald, bf16_t* Bld, int k0) {
#pragma unroll
        for (int c = 0; c < 2; ++c) {
            const int srow = c * 64 + wave * 16;
            gll16(A  + (size_t)(row0 + srow + lr4) * K + k0 + sc, Ald + srow * 32);
            gll16(Bm + (size_t)(col0 + srow + lr4) * K + k0 + sc, Bld + srow * 32);
        }
    };
    auto compute = [&](const bf16_t* Ald, const bf16_t* Bld) {
        bf16x8 af[4], bfr[4];
#pragma unroll
        for (int m = 0; m < 4; ++m)
            af[m] = *(const bf16x8*)(Ald + (wr * 64 + m * 16 + lrow) * 32 + kgrp * 8);
#pragma unroll
        for (int n = 0; n < 4; ++n)
            bfr[n] = *(const bf16x8*)(Bld + (wc * 64 + n * 16 + lrow) * 32 + kgrp * 8);
#pragma unroll
        for (int m = 0; m < 4; ++m)
#pragma unroll
            for (int n = 0; n < 4; ++n)
                acc[m][n] = __builtin_amdgcn_mfma_f32_16x16x32_bf16(
                    af[m], bfr[n], acc[m][n], 0, 0, 0);
    };

    stage(Al0, Bl0, 0);
    __syncthreads();
#pragma unroll 1
    for (int t = 0; t < K / 32; t += 2) {
        stage(Al1, Bl1, (t + 1) * 32);
        compute(Al0, Bl0);
        __syncthreads();
        if (t + 2 < K / 32) stage(Al0, Bl0, (t + 2) * 32);
        compute(Al1, Bl1);
        __syncthreads();
    }
}

// ---------------------------------------------------------------------------
// QK projection: C[r,c] = hsbf[r,:].Wbf[c,:] + bias[c]; c<1024 -> Qbf(b,t,e),
// else Kbf(b,h,t,d).
// ---------------------------------------------------------------------------
__global__ __launch_bounds__(256) void qk_gemm_kernel(
    const bf16_t* __restrict__ hsbf, const bf16_t* __restrict__ Wbf,
    const float* __restrict__ bias,
    bf16_t* __restrict__ Qbf, bf16_t* __restrict__ Kbf)
{
    __shared__ alignas(16) bf16_t Al0[128 * 32], Al1[128 * 32];
    __shared__ alignas(16) bf16_t Bl0[128 * 32], Bl1[128 * 32];

    const int wave = threadIdx.x >> 6;
    const int lane = threadIdx.x & 63;
    const int lrow = lane & 15;
    const int kgrp = lane >> 4;
    const int wr = wave >> 1, wc = wave & 1;
    const int row0 = blockIdx.y * 128;
    const int col0 = blockIdx.x * 128;

    f32x4 acc[4][4] = {};
    gemm_mainloop<EE>(hsbf, Wbf, row0, col0, wave, lane, Al0, Al1, Bl0, Bl1, acc);

#pragma unroll
    for (int n = 0; n < 4; ++n) {
        const int cc = col0 + wc * 64 + n * 16 + lrow;
        const float bv = bias[cc];
#pragma unroll
        for (int m = 0; m < 4; ++m) {
#pragma unroll
            for (int r = 0; r < 4; ++r) {
                const int rr = row0 + wr * 64 + m * 16 + 4 * kgrp + r;
                const float v = acc[m][n][r] + bv;
                const int b = rr >> 11, t = rr & (TT - 1);
                if (cc < EE) {
                    Qbf[(size_t)rr * EE + cc] = (__bf16)v;
                } else {
                    const int h = (cc - EE) >> 6, d = (cc - EE) & 63;
                    Kbf[(((size_t)(b * HH + h)) * TT + t) * DD + d] = (__bf16)v;
                }
            }
        }
    }
}

// ---------------------------------------------------------------------------
// out[b] = rowinv * (dw[b] (TxT bf16) @ hs[b]) with hsT (b,e,t) as B^T.
// ---------------------------------------------------------------------------
__global__ __launch_bounds__(256) void out_gemm_kernel(
    const bf16_t* __restrict__ dwbf, const bf16_t* __restrict__ hsT,
    const float* __restrict__ rowinv, float* __restrict__ out)
{
    __shared__ alignas(16) bf16_t Al0[128 * 32], Al1[128 * 32];
    __shared__ alignas(16) bf16_t Bl0[128 * 32], Bl1[128 * 32];

    const int wave = threadIdx.x >> 6;
    const int lane = threadIdx.x & 63;
    const int lrow = lane & 15;
    const int kgrp = lane >> 4;
    const int wr = wave >> 1, wc = wave & 1;
    const int b = blockIdx.z;
    const int row0 = blockIdx.y * 128;   // within [0,T)
    const int col0 = blockIdx.x * 128;   // within [0,E)

    const bf16_t* A  = dwbf + (size_t)b * TT * TT;
    const bf16_t* Bm = hsT  + (size_t)b * EE * TT;

    f32x4 acc[4][4] = {};
    gemm_mainloop<TT>(A, Bm, row0, col0, wave, lane, Al0, Al1, Bl0, Bl1, acc);

    float ri[4][4];
#pragma unroll
    for (int m = 0; m < 4; ++m)
#pragma unroll
        for (int r = 0; r < 4; ++r)
            ri[m][r] = rowinv[b * TT + row0 + wr * 64 + m * 16 + 4 * kgrp + r];

#pragma unroll
    for (int n = 0; n < 4; ++n) {
        const int cc = col0 + wc * 64 + n * 16 + lrow;
#pragma unroll
        for (int m = 0; m < 4; ++m) {
#pragma unroll
            for (int r = 0; r < 4; ++r) {
                const int rr = row0 + wr * 64 + m * 16 + 4 * kgrp + r;
                out[(size_t)(b * TT + rr) * EE + cc] = acc[m][n][r] * ri[m][r];
            }
        }
    }
}

// ---------------------------------------------------------------------------
// Pass 1: invl[b,h,i] = 1/(H * sum_{j<i} exp(0.125*q_i.k_j)), 0 if empty.
// Block = (i-tile pair {x, 31-x}, h, b). Q frags resident; 4 waves stripe
// j-tiles (32 MFMA + 8 K-loads per tile); shfl + LDS cross-wave reduce.
// ---------------------------------------------------------------------------
__global__ __launch_bounds__(256) void rowsum_kernel(
    const bf16_t* __restrict__ Qbf, const bf16_t* __restrict__ Kbf,
    float* __restrict__ invl_g)
{
    __shared__ float rsp[4][64];
    const int tid = threadIdx.x;
    const int wave = tid >> 6;
    const int lane = tid & 63;
    const int lrow = lane & 15;
    const int kgrp = lane >> 4;
    const int h = blockIdx.y, b = blockIdx.z;
    const bf16_t* Kh = Kbf + (size_t)(b * HH + h) * TT * DD;

#pragma unroll 1
    for (int pick = 0; pick < 2; ++pick) {
        const int it = pick ? (31 - blockIdx.x) : blockIdx.x;
        const int i0 = it * 64;

        bf16x8 af[4][2];
        const bf16_t* qb = Qbf + (size_t)(b * TT + i0 + lrow) * EE + h * DD;
#pragma unroll
        for (int m = 0; m < 4; ++m) {
            af[m][0] = *(const bf16x8*)(qb + (size_t)(m * 16) * EE + kgrp * 8);
            af[m][1] = *(const bf16x8*)(qb + (size_t)(m * 16) * EE + 32 + kgrp * 8);
        }

        f32x4 rs[4] = {};
#pragma unroll 1
        for (int jt = wave; jt <= it; jt += 4) {
            const int j0 = jt * 64;
            const bf16_t* kb = Kh + (size_t)(j0 + lrow) * DD;
            bf16x8 bk[4][2];
#pragma unroll
            for (int n = 0; n < 4; ++n) {
                bk[n][0] = *(const bf16x8*)(kb + (size_t)(n * 16) * DD + kgrp * 8);
                bk[n][1] = *(const bf16x8*)(kb + (size_t)(n * 16) * DD + 32 + kgrp * 8);
            }
#pragma unroll
            for (int m = 0; m < 4; ++m) {
                f32x4 s[4];
#pragma unroll
                for (int n = 0; n < 4; ++n) {
                    s[n] = f32x4{0.f, 0.f, 0.f, 0.f};
                    s[n] = __builtin_amdgcn_mfma_f32_16x16x32_bf16(af[m][0], bk[n][0], s[n], 0, 0, 0);
                    s[n] = __builtin_amdgcn_mfma_f32_16x16x32_bf16(af[m][1], bk[n][1], s[n], 0, 0, 0);
                }
                if (jt == it) {
#pragma unroll
                    for (int n = 0; n < 4; ++n)
#pragma unroll
                        for (int r = 0; r < 4; ++r) {
                            const int jj = j0 + n * 16 + lrow;
                            const int ii = i0 + m * 16 + 4 * kgrp + r;
                            if (jj < ii) rs[m][r] += __expf(0.125f * s[n][r]);
                        }
                } else {
#pragma unroll
                    for (int n = 0; n < 4; ++n)
#pragma unroll
                        for (int r = 0; r < 4; ++r)
                            rs[m][r] += __expf(0.125f * s[n][r]);
                }
            }
        }
#pragma unroll
        for (int off = 1; off < 16; off <<= 1)
#pragma unroll
            for (int m = 0; m < 4; ++m)
#pragma unroll
                for (int r = 0; r < 4; ++r)
                    rs[m][r] += __shfl_xor(rs[m][r], off);
        if (lrow == 0) {
#pragma unroll
            for (int m = 0; m < 4; ++m)
#pragma unroll
                for (int r = 0; r < 4; ++r)
                    rsp[wave][m * 16 + 4 * kgrp + r] = rs[m][r];
        }
        __syncthreads();
        if (tid < 64) {
            const float tot = rsp[0][tid] + rsp[1][tid] + rsp[2][tid] + rsp[3][tid];
            invl_g[(size_t)(b * HH + h) * TT + i0 + tid] =
                (tot > 0.f) ? 1.0f / (tot * (float)HH) : 0.f;
        }
        __syncthreads();
    }
}

// ---------------------------------------------------------------------------
// Pass 2: one full 64x64 lower-triangle tile PER WAVE (tri-decoded).
// Per head: 16 indep 16B loads -> 32 MFMA (16 chains); avg += exp(s)*invl.
// Epilogue in-register: clip+gumbel+exp -> unnormalized bf16 store.
// ---------------------------------------------------------------------------
__global__ __launch_bounds__(256) void dw_tile_kernel(
    const bf16_t* __restrict__ Qbf, const bf16_t* __restrict__ Kbf,
    const float* __restrict__ invl_g, bf16_t* __restrict__ dwbf)
{
    const int wave = threadIdx.x >> 6;
    const int lane = threadIdx.x & 63;
    const int lrow = lane & 15;
    const int kgrp = lane >> 4;
    const int tidx = blockIdx.x * 4 + wave;      // 0..527
    const int b = blockIdx.y;

    int it = (int)((sqrtf(8.0f * tidx + 1.0f) - 1.0f) * 0.5f);
    while ((it + 1) * (it + 2) / 2 <= tidx) ++it;
    while (it * (it + 1) / 2 > tidx) --it;
    const int jt = tidx - it * (it + 1) / 2;
    const bool diag = (it == jt);
    const int i0 = it * 64, j0 = jt * 64;

    f32x4 avg[4][4] = {};

#pragma unroll 1
    for (int h = 0; h < HH; ++h) {
        const bf16_t* qb = Qbf + (size_t)(b * TT + i0 + lrow) * EE + h * DD;
        const bf16_t* kb = Kbf + ((size_t)(b * HH + h) * TT + j0 + lrow) * DD;
        bf16x8 af[4][2], bk[4][2];
#pragma unroll
        for (int m = 0; m < 4; ++m) {
            af[m][0] = *(const bf16x8*)(qb + (size_t)(m * 16) * EE + kgrp * 8);
            af[m][1] = *(const bf16x8*)(qb + (size_t)(m * 16) * EE + 32 + kgrp * 8);
        }
#pragma unroll
        for (int n = 0; n < 4; ++n) {
            bk[n][0] = *(const bf16x8*)(kb + (size_t)(n * 16) * DD + kgrp * 8);
            bk[n][1] = *(const bf16x8*)(kb + (size_t)(n * 16) * DD + 32 + kgrp * 8);
        }
        f32x4 ri[4];
#pragma unroll
        for (int m = 0; m < 4; ++m)
            ri[m] = *(const f32x4*)(invl_g + (size_t)(b * HH + h) * TT + i0 + m * 16 + 4 * kgrp);

#pragma unroll
        for (int m = 0; m < 4; ++m) {
            const int nlim = diag ? (m + 1) : 4;
            f32x4 s[4];
#pragma unroll
            for (int n = 0; n < 4; ++n) {
                if (n < nlim) {
                    s[n] = f32x4{0.f, 0.f, 0.f, 0.f};
                    s[n] = __builtin_amdgcn_mfma_f32_16x16x32_bf16(af[m][0], bk[n][0], s[n], 0, 0, 0);
                    s[n] = __builtin_amdgcn_mfma_f32_16x16x32_bf16(af[m][1], bk[n][1], s[n], 0, 0, 0);
                }
            }
#pragma unroll
            for (int n = 0; n < 4; ++n) {
                if (n < nlim) {
#pragma unroll
                    for (int r = 0; r < 4; ++r)
                        avg[m][n][r] += __expf(0.125f * s[n][r]) * ri[m][r];
                }
            }
        }
    }

    // epilogue: clip + gumbel + exp -> bf16 store (masked cells untouched)
#pragma unroll
    for (int m = 0; m < 4; ++m) {
#pragma unroll
        for (int n = 0; n < 4; ++n) {
            if (!diag || n <= m) {
                const int jj = j0 + n * 16 + lrow;
#pragma unroll
                for (int r = 0; r < 4; ++r) {
                    const int ii = i0 + m * 16 + 4 * kgrp + r;
                    if (jj < ii) {
                        const float lg = fminf(fmaxf(avg[m][n][r], -40.0f), 40.0f);
                        const float g = gumbel_for((unsigned)(b * TT + ii) * TT + (unsigned)jj);
                        dwbf[(size_t)(b * TT + ii) * TT + jj] = (__bf16)__expf((lg + g) * 0.5f);
                    }
                }
            }
        }
    }
}

// ---------------------------------------------------------------------------
// rowinv[b*T+i] = 1 / sum_j dwbf[b,i,j] (upper triangle is 0 via memset).
// ---------------------------------------------------------------------------
__global__ __launch_bounds__(256) void rowinv_kernel(
    const bf16_t* __restrict__ dwbf, float* __restrict__ rowinv)
{
    __shared__ float red[256];
    const int blk = blockIdx.x;           // b*T + i
    const int i = blk & (TT - 1);
    const int tid = threadIdx.x;
    const bf16_t* row = dwbf + (size_t)blk * TT;

    bf16x8 v = *(const bf16x8*)(row + tid * 8);
    float s = 0.f;
#pragma unroll
    for (int e = 0; e < 8; ++e) s += (float)v[e];
    red[tid] = s; __syncthreads();
    for (int st = 128; st > 0; st >>= 1) {
        if (tid < st) red[tid] += red[tid + st];
        __syncthreads();
    }
    if (tid == 0)
        rowinv[blk] = (i > 0 && red[0] > 0.f) ? 1.0f / red[0] : 0.f;
}

// ---------------------------------------------------------------------------
extern "C" void kernel_launch(void* const* d_in, const int* in_sizes, int n_in,
                              void* d_out, int out_size, void* d_ws, size_t ws_size,
                              hipStream_t stream) {
    const float* hs   = (const float*)d_in[0];   // (B,T,E) f32
    const float* W    = (const float*)d_in[1];   // (3E,E)  f32
    const float* bias = (const float*)d_in[2];   // (3E,)   f32
    float* out = (float*)d_out;                  // (B,T,E) f32

    char* ws = (char*)d_ws;
    bf16_t* dwbf   = (bf16_t*)ws;                                  // 16 MB (b,i,j)
    bf16_t* Qbf    = (bf16_t*)(ws + (size_t)16 * 1024 * 1024);     //  8 MB (b,t,e)
    bf16_t* Kbf    = (bf16_t*)(ws + (size_t)24 * 1024 * 1024);     //  8 MB (b,h,t,d)
    bf16_t* hsbf   = (bf16_t*)(ws + (size_t)32 * 1024 * 1024);     //  8 MB
    bf16_t* Wbf    = (bf16_t*)(ws + (size_t)40 * 1024 * 1024);     //  4 MB
    bf16_t* hsT    = (bf16_t*)(ws + (size_t)44 * 1024 * 1024);     //  8 MB (b,e,t)
    float*  invl_g = (float*) (ws + (size_t)52 * 1024 * 1024);     // 256 KB
    float*  rowinv = (float*) (ws + (size_t)52 * 1024 * 1024 + 256 * 1024); // 16 KB

    hipMemsetAsync(dwbf, 0, (size_t)16 * 1024 * 1024, stream);
    convert_kernel<<<2048, 256, 0, stream>>>(hs, W, hsbf, Wbf);
    transpose_kernel<<<dim3(EE / 64, TT / 64, BB), 256, 0, stream>>>(hs, hsT);
    qk_gemm_kernel<<<dim3(2048 / 128, 4096 / 128), 256, 0, stream>>>(hsbf, Wbf, bias, Qbf, Kbf);
    rowsum_kernel<<<dim3(16, HH, BB), 256, 0, stream>>>(Qbf, Kbf, invl_g);
    dw_tile_kernel<<<dim3(132, BB), 256, 0, stream>>>(Qbf, Kbf, invl_g, dwbf);
    rowinv_kernel<<<BB * TT, 256, 0, stream>>>(dwbf, rowinv);
    out_gemm_kernel<<<dim3(EE / 128, TT / 128, BB), 256, 0, stream>>>(dwbf, hsT, rowinv, out);
}

// Round 9
// 196.091 us; speedup vs baseline: 13.2953x; 1.1169x over previous
//
#include <hip/hip_runtime.h>
#include <math.h>

// Problem constants: B=2, T=2048, E=1024, H=16, D=64
#define TT 2048
#define EE 1024
#define HH 16
#define DD 64
#define BB 2

typedef __bf16 bf16_t;
typedef __attribute__((ext_vector_type(8))) __bf16 bf16x8;
typedef __attribute__((ext_vector_type(4))) float f32x4;

__device__ __forceinline__ unsigned short f2b(float v) {
    return __builtin_bit_cast(unsigned short, (__bf16)v);
}

// async global->LDS, 16B per lane; LDS dest = wave-uniform base + lane*16
__device__ __forceinline__ void gll16(const void* g, void* l) {
    __builtin_amdgcn_global_load_lds(
        (const __attribute__((address_space(1))) void*)g,
        (__attribute__((address_space(3))) void*)l, 16, 0, 0);
}

// ---------------------------------------------------------------------------
// Threefry-2x32, JAX partitionable stream, key=(0,42). Verified round 3.
// ---------------------------------------------------------------------------
__device__ __forceinline__ unsigned int rotl32(unsigned int x, int r) {
    return (x << r) | (x >> (32 - r));
}

__device__ __forceinline__ float gumbel_for(unsigned int f) {
    const unsigned int ks0 = 0u;
    const unsigned int ks1 = 42u;
    const unsigned int ks2 = 0x1BD11BDAu ^ ks0 ^ ks1;

    unsigned int v0 = 0u + ks0;
    unsigned int v1 = f  + ks1;

    v0 += v1; v1 = rotl32(v1, 13); v1 ^= v0;
    v0 += v1; v1 = rotl32(v1, 15); v1 ^= v0;
    v0 += v1; v1 = rotl32(v1, 26); v1 ^= v0;
    v0 += v1; v1 = rotl32(v1,  6); v1 ^= v0;
    v0 += ks1; v1 += ks2 + 1u;
    v0 += v1; v1 = rotl32(v1, 17); v1 ^= v0;
    v0 += v1; v1 = rotl32(v1, 29); v1 ^= v0;
    v0 += v1; v1 = rotl32(v1, 16); v1 ^= v0;
    v0 += v1; v1 = rotl32(v1, 24); v1 ^= v0;
    v0 += ks2; v1 += ks0 + 2u;
    v0 += v1; v1 = rotl32(v1, 13); v1 ^= v0;
    v0 += v1; v1 = rotl32(v1, 15); v1 ^= v0;
    v0 += v1; v1 = rotl32(v1, 26); v1 ^= v0;
    v0 += v1; v1 = rotl32(v1,  6); v1 ^= v0;
    v0 += ks0; v1 += ks1 + 3u;
    v0 += v1; v1 = rotl32(v1, 17); v1 ^= v0;
    v0 += v1; v1 = rotl32(v1, 29); v1 ^= v0;
    v0 += v1; v1 = rotl32(v1, 16); v1 ^= v0;
    v0 += v1; v1 = rotl32(v1, 24); v1 ^= v0;
    v0 += ks1; v1 += ks2 + 4u;
    v0 += v1; v1 = rotl32(v1, 13); v1 ^= v0;
    v0 += v1; v1 = rotl32(v1, 15); v1 ^= v0;
    v0 += v1; v1 = rotl32(v1, 26); v1 ^= v0;
    v0 += v1; v1 = rotl32(v1,  6); v1 ^= v0;
    v0 += ks2; v1 += ks0 + 5u;

    unsigned int bits = v0 ^ v1;
    unsigned int fb = (bits >> 9) | 0x3F800000u;
    float u01 = __uint_as_float(fb) - 1.0f;
    const float mn = 1e-6f;
    const float mx = 1.0f - 1e-6f;
    float u = fmaxf(mn, u01 * (mx - mn) + mn);
    return -__logf(-__logf(u));
}

// ---------------------------------------------------------------------------
// Convert hs (4M f32) and W[0:2048] (2M f32) to bf16.
// ---------------------------------------------------------------------------
__global__ __launch_bounds__(256) void convert_kernel(
    const float* __restrict__ hs, const float* __restrict__ W,
    bf16_t* __restrict__ hsbf, bf16_t* __restrict__ Wbf)
{
    const int n1 = BB * TT * EE / 4;
    const int n2 = 2 * EE * EE / 4;
    const int total = n1 + n2;
    for (int idx = blockIdx.x * 256 + threadIdx.x; idx < total;
         idx += gridDim.x * 256) {
        float4 v = (idx < n1) ? ((const float4*)hs)[idx]
                              : ((const float4*)W)[idx - n1];
        ushort4 o;
        o.x = f2b(v.x); o.y = f2b(v.y); o.z = f2b(v.z); o.w = f2b(v.w);
        if (idx < n1) ((ushort4*)hsbf)[idx] = o;
        else          ((ushort4*)Wbf)[idx - n1] = o;
    }
}

// ---------------------------------------------------------------------------
// Transpose hs -> hsT bf16: hsT[b][e][t] = hs[b][t][e]
// ---------------------------------------------------------------------------
__global__ __launch_bounds__(256) void transpose_kernel(
    const float* __restrict__ hs, bf16_t* __restrict__ hsT)
{
    __shared__ float ts[64][65];
    const int e0 = blockIdx.x * 64;
    const int t0 = blockIdx.y * 64;
    const int b  = blockIdx.z;
    const int tid = threadIdx.x;
#pragma unroll
    for (int it = 0; it < 16; ++it) {
        const int idx = it * 256 + tid;
        const int tr = idx >> 6, te = idx & 63;
        ts[tr][te] = hs[((size_t)(b * TT + t0 + tr)) * EE + e0 + te];
    }
    __syncthreads();
#pragma unroll
    for (int it = 0; it < 16; ++it) {
        const int idx = it * 256 + tid;
        const int er = idx >> 6, tc = idx & 63;
        hsT[((size_t)(b * EE + e0 + er)) * TT + t0 + tc] = (__bf16)ts[tc][er];
    }
}

// ---------------------------------------------------------------------------
// Shared 128x128-tile GEMM main loop (m97 structure): C = A[M,K] . B[N,K]^T.
// ---------------------------------------------------------------------------
template <int K>
__device__ __forceinline__ void gemm_mainloop(
    const bf16_t* __restrict__ A, const bf16_t* __restrict__ Bm,
    int row0, int col0, int wave, int lane,
    bf16_t* Al0, bf16_t* Al1, bf16_t* Bl0, bf16_t* Bl1,
    f32x4 (&acc)[4][4])
{
    const int lrow = lane & 15;
    const int kgrp = lane >> 4;
    const int wr = wave >> 1, wc = wave & 1;
    const int lr4 = lane >> 2;        // staging row within 16
    const int sc  = (lane & 3) * 8;   // staging col (elements)

    auto stage = [&](bf16_t* Ald, bf16_t* Bld, int k0) {
#pragma unroll
        for (int c = 0; c < 2; ++c) {
            const int srow = c * 64 + wave * 16;
            gll16(A  + (size_t)(row0 + srow + lr4) * K + k0 + sc, Ald + srow * 32);
            gll16(Bm + (size_t)(col0 + srow + lr4) * K + k0 + sc, Bld + srow * 32);
        }
    };
    auto compute = [&](const bf16_t* Ald, const bf16_t* Bld) {
        bf16x8 af[4], bfr[4];
#pragma unroll
        for (int m = 0; m < 4; ++m)
            af[m] = *(const bf16x8*)(Ald + (wr * 64 + m * 16 + lrow) * 32 + kgrp * 8);
#pragma unroll
        for (int n = 0; n < 4; ++n)
            bfr[n] = *(const bf16x8*)(Bld + (wc * 64 + n * 16 + lrow) * 32 + kgrp * 8);
#pragma unroll
        for (int m = 0; m < 4; ++m)
#pragma unroll
            for (int n = 0; n < 4; ++n)
                acc[m][n] = __builtin_amdgcn_mfma_f32_16x16x32_bf16(
                    af[m], bfr[n], acc[m][n], 0, 0, 0);
    };

    stage(Al0, Bl0, 0);
    __syncthreads();
#pragma unroll 1
    for (int t = 0; t < K / 32; t += 2) {
        stage(Al1, Bl1, (t + 1) * 32);
        compute(Al0, Bl0);
        __syncthreads();
        if (t + 2 < K / 32) stage(Al0, Bl0, (t + 2) * 32);
        compute(Al1, Bl1);
        __syncthreads();
    }
}

// ---------------------------------------------------------------------------
// QK projection: C[r,c] = hsbf[r,:].Wbf[c,:] + bias[c]; c<1024 -> Qbf(b,t,e),
// else Kbf(b,h,t,d).
// ---------------------------------------------------------------------------
__global__ __launch_bounds__(256) void qk_gemm_kernel(
    const bf16_t* __restrict__ hsbf, const bf16_t* __restrict__ Wbf,
    const float* __restrict__ bias,
    bf16_t* __restrict__ Qbf, bf16_t* __restrict__ Kbf)
{
    __shared__ alignas(16) bf16_t Al0[128 * 32], Al1[128 * 32];
    __shared__ alignas(16) bf16_t Bl0[128 * 32], Bl1[128 * 32];

    const int wave = threadIdx.x >> 6;
    const int lane = threadIdx.x & 63;
    const int lrow = lane & 15;
    const int kgrp = lane >> 4;
    const int wr = wave >> 1, wc = wave & 1;
    const int row0 = blockIdx.y * 128;
    const int col0 = blockIdx.x * 128;

    f32x4 acc[4][4] = {};
    gemm_mainloop<EE>(hsbf, Wbf, row0, col0, wave, lane, Al0, Al1, Bl0, Bl1, acc);

#pragma unroll
    for (int n = 0; n < 4; ++n) {
        const int cc = col0 + wc * 64 + n * 16 + lrow;
        const float bv = bias[cc];
#pragma unroll
        for (int m = 0; m < 4; ++m) {
#pragma unroll
            for (int r = 0; r < 4; ++r) {
                const int rr = row0 + wr * 64 + m * 16 + 4 * kgrp + r;
                const float v = acc[m][n][r] + bv;
                const int b = rr >> 11, t = rr & (TT - 1);
                if (cc < EE) {
                    Qbf[(size_t)rr * EE + cc] = (__bf16)v;
                } else {
                    const int h = (cc - EE) >> 6, d = (cc - EE) & 63;
                    Kbf[(((size_t)(b * HH + h)) * TT + t) * DD + d] = (__bf16)v;
                }
            }
        }
    }
}

// ---------------------------------------------------------------------------
// out[b] = rowinv * (dw[b] (TxT bf16) @ hs[b]) with hsT (b,e,t) as B^T.
// ---------------------------------------------------------------------------
__global__ __launch_bounds__(256) void out_gemm_kernel(
    const bf16_t* __restrict__ dwbf, const bf16_t* __restrict__ hsT,
    const float* __restrict__ rowinv, float* __restrict__ out)
{
    __shared__ alignas(16) bf16_t Al0[128 * 32], Al1[128 * 32];
    __shared__ alignas(16) bf16_t Bl0[128 * 32], Bl1[128 * 32];

    const int wave = threadIdx.x >> 6;
    const int lane = threadIdx.x & 63;
    const int lrow = lane & 15;
    const int kgrp = lane >> 4;
    const int wr = wave >> 1, wc = wave & 1;
    const int b = blockIdx.z;
    const int row0 = blockIdx.y * 128;   // within [0,T)
    const int col0 = blockIdx.x * 128;   // within [0,E)

    const bf16_t* A  = dwbf + (size_t)b * TT * TT;
    const bf16_t* Bm = hsT  + (size_t)b * EE * TT;

    f32x4 acc[4][4] = {};
    gemm_mainloop<TT>(A, Bm, row0, col0, wave, lane, Al0, Al1, Bl0, Bl1, acc);

    float ri[4][4];
#pragma unroll
    for (int m = 0; m < 4; ++m)
#pragma unroll
        for (int r = 0; r < 4; ++r)
            ri[m][r] = rowinv[b * TT + row0 + wr * 64 + m * 16 + 4 * kgrp + r];

#pragma unroll
    for (int n = 0; n < 4; ++n) {
        const int cc = col0 + wc * 64 + n * 16 + lrow;
#pragma unroll
        for (int m = 0; m < 4; ++m) {
#pragma unroll
            for (int r = 0; r < 4; ++r) {
                const int rr = row0 + wr * 64 + m * 16 + 4 * kgrp + r;
                out[(size_t)(b * TT + rr) * EE + cc] = acc[m][n][r] * ri[m][r];
            }
        }
    }
}

// ---------------------------------------------------------------------------
// Pass 1: invl[b,h,i] = 1/(H * sum_{j<i} exp(0.125*q_i.k_j)), 0 if empty.
// Block = (i-tile pair {x, 31-x}, h, b). Q frags resident; 4 waves stripe
// j-tiles (32 MFMA + 8 K-loads per tile); shfl + LDS cross-wave reduce.
// ---------------------------------------------------------------------------
__global__ __launch_bounds__(256) void rowsum_kernel(
    const bf16_t* __restrict__ Qbf, const bf16_t* __restrict__ Kbf,
    float* __restrict__ invl_g)
{
    __shared__ float rsp[4][64];
    const int tid = threadIdx.x;
    const int wave = tid >> 6;
    const int lane = tid & 63;
    const int lrow = lane & 15;
    const int kgrp = lane >> 4;
    const int h = blockIdx.y, b = blockIdx.z;
    const bf16_t* Kh = Kbf + (size_t)(b * HH + h) * TT * DD;

#pragma unroll 1
    for (int pick = 0; pick < 2; ++pick) {
        const int it = pick ? (31 - blockIdx.x) : blockIdx.x;
        const int i0 = it * 64;

        bf16x8 af[4][2];
        const bf16_t* qb = Qbf + (size_t)(b * TT + i0 + lrow) * EE + h * DD;
#pragma unroll
        for (int m = 0; m < 4; ++m) {
            af[m][0] = *(const bf16x8*)(qb + (size_t)(m * 16) * EE + kgrp * 8);
            af[m][1] = *(const bf16x8*)(qb + (size_t)(m * 16) * EE + 32 + kgrp * 8);
        }

        f32x4 rs[4] = {};
#pragma unroll 1
        for (int jt = wave; jt <= it; jt += 4) {
            const int j0 = jt * 64;
            const bf16_t* kb = Kh + (size_t)(j0 + lrow) * DD;
            bf16x8 bk[4][2];
#pragma unroll
            for (int n = 0; n < 4; ++n) {
                bk[n][0] = *(const bf16x8*)(kb + (size_t)(n * 16) * DD + kgrp * 8);
                bk[n][1] = *(const bf16x8*)(kb + (size_t)(n * 16) * DD + 32 + kgrp * 8);
            }
#pragma unroll
            for (int m = 0; m < 4; ++m) {
                f32x4 s[4];
#pragma unroll
                for (int n = 0; n < 4; ++n) {
                    s[n] = f32x4{0.f, 0.f, 0.f, 0.f};
                    s[n] = __builtin_amdgcn_mfma_f32_16x16x32_bf16(af[m][0], bk[n][0], s[n], 0, 0, 0);
                    s[n] = __builtin_amdgcn_mfma_f32_16x16x32_bf16(af[m][1], bk[n][1], s[n], 0, 0, 0);
                }
                if (jt == it) {
#pragma unroll
                    for (int n = 0; n < 4; ++n)
#pragma unroll
                        for (int r = 0; r < 4; ++r) {
                            const int jj = j0 + n * 16 + lrow;
                            const int ii = i0 + m * 16 + 4 * kgrp + r;
                            if (jj < ii) rs[m][r] += __expf(0.125f * s[n][r]);
                        }
                } else {
#pragma unroll
                    for (int n = 0; n < 4; ++n)
#pragma unroll
                        for (int r = 0; r < 4; ++r)
                            rs[m][r] += __expf(0.125f * s[n][r]);
                }
            }
        }
#pragma unroll
        for (int off = 1; off < 16; off <<= 1)
#pragma unroll
            for (int m = 0; m < 4; ++m)
#pragma unroll
                for (int r = 0; r < 4; ++r)
                    rs[m][r] += __shfl_xor(rs[m][r], off);
        if (lrow == 0) {
#pragma unroll
            for (int m = 0; m < 4; ++m)
#pragma unroll
                for (int r = 0; r < 4; ++r)
                    rsp[wave][m * 16 + 4 * kgrp + r] = rs[m][r];
        }
        __syncthreads();
        if (tid < 64) {
            const float tot = rsp[0][tid] + rsp[1][tid] + rsp[2][tid] + rsp[3][tid];
            invl_g[(size_t)(b * HH + h) * TT + i0 + tid] =
                (tot > 0.f) ? 1.0f / (tot * (float)HH) : 0.f;
        }
        __syncthreads();
    }
}

// ---------------------------------------------------------------------------
// Pass 2: block = one 64x64 lower-triangle tile; 4 waves split the 16 heads
// (4 each), full-tile MFMA per wave (16 indep chains), LDS-reduced avg,
// parallel epilogue (wave m owns row-fragment m).
// ---------------------------------------------------------------------------
__global__ __launch_bounds__(256) void dw_tile_kernel(
    const bf16_t* __restrict__ Qbf, const bf16_t* __restrict__ Kbf,
    const float* __restrict__ invl_g, bf16_t* __restrict__ dwbf)
{
    __shared__ float red[4][64][17];   // stride 17: conflict-free scalar access

    const int wave = threadIdx.x >> 6;
    const int lane = threadIdx.x & 63;
    const int lrow = lane & 15;
    const int kgrp = lane >> 4;
    const int tidx = blockIdx.x;       // 0..527
    const int b = blockIdx.y;

    int it = (int)((sqrtf(8.0f * tidx + 1.0f) - 1.0f) * 0.5f);
    while ((it + 1) * (it + 2) / 2 <= tidx) ++it;
    while (it * (it + 1) / 2 > tidx) --it;
    const int jt = tidx - it * (it + 1) / 2;
    const bool diag = (it == jt);
    const int i0 = it * 64, j0 = jt * 64;

    f32x4 avg[4][4] = {};

#pragma unroll 1
    for (int hh = 0; hh < HH / 4; ++hh) {
        const int h = wave * 4 + hh;
        const bf16_t* qb = Qbf + (size_t)(b * TT + i0 + lrow) * EE + h * DD;
        const bf16_t* kb = Kbf + ((size_t)(b * HH + h) * TT + j0 + lrow) * DD;
        bf16x8 af[4][2], bk[4][2];
#pragma unroll
        for (int m = 0; m < 4; ++m) {
            af[m][0] = *(const bf16x8*)(qb + (size_t)(m * 16) * EE + kgrp * 8);
            af[m][1] = *(const bf16x8*)(qb + (size_t)(m * 16) * EE + 32 + kgrp * 8);
        }
#pragma unroll
        for (int n = 0; n < 4; ++n) {
            bk[n][0] = *(const bf16x8*)(kb + (size_t)(n * 16) * DD + kgrp * 8);
            bk[n][1] = *(const bf16x8*)(kb + (size_t)(n * 16) * DD + 32 + kgrp * 8);
        }
        f32x4 ri[4];
#pragma unroll
        for (int m = 0; m < 4; ++m)
            ri[m] = *(const f32x4*)(invl_g + (size_t)(b * HH + h) * TT + i0 + m * 16 + 4 * kgrp);

#pragma unroll
        for (int m = 0; m < 4; ++m) {
            const int nlim = diag ? (m + 1) : 4;
            f32x4 s[4];
#pragma unroll
            for (int n = 0; n < 4; ++n) {
                if (n < nlim) {
                    s[n] = f32x4{0.f, 0.f, 0.f, 0.f};
                    s[n] = __builtin_amdgcn_mfma_f32_16x16x32_bf16(af[m][0], bk[n][0], s[n], 0, 0, 0);
                    s[n] = __builtin_amdgcn_mfma_f32_16x16x32_bf16(af[m][1], bk[n][1], s[n], 0, 0, 0);
                }
            }
#pragma unroll
            for (int n = 0; n < 4; ++n) {
                if (n < nlim) {
#pragma unroll
                    for (int r = 0; r < 4; ++r)
                        avg[m][n][r] += __expf(0.125f * s[n][r]) * ri[m][r];
                }
            }
        }
    }

    // cross-wave head-reduce: 4 rounds; wave m keeps summed avg for frag m
    float sum[4][4];                   // [n][r] for my m = wave
#pragma unroll 1
    for (int m = 0; m < 4; ++m) {
#pragma unroll
        for (int n = 0; n < 4; ++n)
#pragma unroll
            for (int r = 0; r < 4; ++r)
                red[wave][lane][n * 4 + r] = avg[m][n][r];
        __syncthreads();
        if (wave == m) {
#pragma unroll
            for (int n = 0; n < 4; ++n)
#pragma unroll
                for (int r = 0; r < 4; ++r)
                    sum[n][r] = red[0][lane][n * 4 + r] + red[1][lane][n * 4 + r]
                              + red[2][lane][n * 4 + r] + red[3][lane][n * 4 + r];
        }
        __syncthreads();
    }

    // parallel epilogue: wave m owns rows i0 + m*16 .. +15
    const int m = wave;
#pragma unroll
    for (int n = 0; n < 4; ++n) {
        if (!diag || n <= m) {
            const int jj = j0 + n * 16 + lrow;
#pragma unroll
            for (int r = 0; r < 4; ++r) {
                const int ii = i0 + m * 16 + 4 * kgrp + r;
                if (jj < ii) {
                    const float lg = fminf(fmaxf(sum[n][r], -40.0f), 40.0f);
                    const float g = gumbel_for((unsigned)(b * TT + ii) * TT + (unsigned)jj);
                    dwbf[(size_t)(b * TT + ii) * TT + jj] = (__bf16)__expf((lg + g) * 0.5f);
                }
            }
        }
    }
}

// ---------------------------------------------------------------------------
// rowinv[b*T+i] = 1 / sum_j dwbf[b,i,j] (upper triangle is 0 via memset).
// ---------------------------------------------------------------------------
__global__ __launch_bounds__(256) void rowinv_kernel(
    const bf16_t* __restrict__ dwbf, float* __restrict__ rowinv)
{
    __shared__ float red[256];
    const int blk = blockIdx.x;           // b*T + i
    const int i = blk & (TT - 1);
    const int tid = threadIdx.x;
    const bf16_t* row = dwbf + (size_t)blk * TT;

    bf16x8 v = *(const bf16x8*)(row + tid * 8);
    float s = 0.f;
#pragma unroll
    for (int e = 0; e < 8; ++e) s += (float)v[e];
    red[tid] = s; __syncthreads();
    for (int st = 128; st > 0; st >>= 1) {
        if (tid < st) red[tid] += red[tid + st];
        __syncthreads();
    }
    if (tid == 0)
        rowinv[blk] = (i > 0 && red[0] > 0.f) ? 1.0f / red[0] : 0.f;
}

// ---------------------------------------------------------------------------
extern "C" void kernel_launch(void* const* d_in, const int* in_sizes, int n_in,
                              void* d_out, int out_size, void* d_ws, size_t ws_size,
                              hipStream_t stream) {
    const float* hs   = (const float*)d_in[0];   // (B,T,E) f32
    const float* W    = (const float*)d_in[1];   // (3E,E)  f32
    const float* bias = (const float*)d_in[2];   // (3E,)   f32
    float* out = (float*)d_out;                  // (B,T,E) f32

    char* ws = (char*)d_ws;
    bf16_t* dwbf   = (bf16_t*)ws;                                  // 16 MB (b,i,j)
    bf16_t* Qbf    = (bf16_t*)(ws + (size_t)16 * 1024 * 1024);     //  8 MB (b,t,e)
    bf16_t* Kbf    = (bf16_t*)(ws + (size_t)24 * 1024 * 1024);     //  8 MB (b,h,t,d)
    bf16_t* hsbf   = (bf16_t*)(ws + (size_t)32 * 1024 * 1024);     //  8 MB
    bf16_t* Wbf    = (bf16_t*)(ws + (size_t)40 * 1024 * 1024);     //  4 MB
    bf16_t* hsT    = (bf16_t*)(ws + (size_t)44 * 1024 * 1024);     //  8 MB (b,e,t)
    float*  invl_g = (float*) (ws + (size_t)52 * 1024 * 1024);     // 256 KB
    float*  rowinv = (float*) (ws + (size_t)52 * 1024 * 1024 + 256 * 1024); // 16 KB

    hipMemsetAsync(dwbf, 0, (size_t)16 * 1024 * 1024, stream);
    convert_kernel<<<2048, 256, 0, stream>>>(hs, W, hsbf, Wbf);
    transpose_kernel<<<dim3(EE / 64, TT / 64, BB), 256, 0, stream>>>(hs, hsT);
    qk_gemm_kernel<<<dim3(2048 / 128, 4096 / 128), 256, 0, stream>>>(hsbf, Wbf, bias, Qbf, Kbf);
    rowsum_kernel<<<dim3(16, HH, BB), 256, 0, stream>>>(Qbf, Kbf, invl_g);
    dw_tile_kernel<<<dim3(528, BB), 256, 0, stream>>>(Qbf, Kbf, invl_g, dwbf);
    rowinv_kernel<<<BB * TT, 256, 0, stream>>>(dwbf, rowinv);
    out_gemm_kernel<<<dim3(EE / 128, TT / 128, BB), 256, 0, stream>>>(dwbf, hsT, rowinv, out);
}